// Round 8
// baseline (6012.596 us; speedup 1.0000x reference)
//
#include <hip/hip_runtime.h>
#include <math.h>

#define NN 512
#define BB 32
#define UU 64
#define CC 128
#define TT 12
#define NP 12
#define RRR (NN*BB)   // 16384 rows = (n,b)

typedef _Float16 f16;
typedef f16 f16x8 __attribute__((ext_vector_type(8)));
typedef f16 f16x4 __attribute__((ext_vector_type(4)));
typedef f16 f16x2 __attribute__((ext_vector_type(2)));
typedef float f32x4 __attribute__((ext_vector_type(4)));

// direct global->LDS DMA, 16B per lane; dst wave-uniform base (lane*16 added by HW)
__device__ __forceinline__ void gload16(const f16* g, f16* l) {
  __builtin_amdgcn_global_load_lds((const __attribute__((address_space(1))) void*)g,
                                   (__attribute__((address_space(3))) void*)l, 16, 0, 0);
}

// ---- workspace layout (float units) ----
static const size_t OFF_ST    = 0;                              // [4][512][512] f32
static const size_t OFF_AH    = OFF_ST   + (size_t)4*512*512;
static const size_t OFF_INVD  = OFF_AH   + (size_t)2*512*512;
static const size_t OFF_HT0   = OFF_INVD + 2048;                // 2 x (2048*512 f16)
static const size_t OFF_H     = OFF_HT0  + 2*524288;            // [2][16384][64] f32
static const size_t OFF_U     = OFF_H    + (size_t)2*RRR*UU;
static const size_t OFF_SX    = OFF_U    + (size_t)2*RRR*UU;    // 16384 f32
static const size_t OFF_PS    = OFF_SX   + 16384;               // 4*512*32 f32
static const size_t OFF_SROW  = OFF_PS   + 65536;               // 2048 f32
static const size_t OFF_F16   = OFF_SROW + 2048;
// f16 regions (float units = f16count/2)
static const size_t OFF_ST16A = OFF_F16;                        // 2048*512 f16
static const size_t OFF_ST16B = OFF_ST16A + 524288;
static const size_t OFF_XHT1  = OFF_ST16B + 524288;             // 4096*512 f16
static const size_t OFF_XHT2  = OFF_XHT1  + 1048576;
static const size_t OFF_RHT1  = OFF_XHT2  + 1048576;            // 2*2048*512 f16
static const size_t OFF_RHT2  = OFF_RHT1  + 1048576;
static const size_t OFF_P1    = OFF_RHT2  + 1048576;            // 2048*4096 f16
static const size_t OFF_P2    = OFF_P1    + 4194304;
static const size_t OFF_Q1    = OFF_P2    + 4194304;            // 4*512*2048 f16
static const size_t OFF_Q2    = OFF_Q1    + 2097152;
static const size_t OFF_WT1   = OFF_Q2    + 2097152;            // 393216 f16
static const size_t OFF_WT2   = OFF_WT1   + 196608;

// ---------- precompute ----------
__global__ void k_build_ah(const float* __restrict__ adj, const float* __restrict__ sm1,
                           const float* __restrict__ sm2, float* __restrict__ ah) {
  int a = blockIdx.y, i = blockIdx.x;
  const float* sm = a ? sm2 : sm1;
  for (int j = threadIdx.x; j < NN; j += blockDim.x) {
    float m = tanhf(0.5f * (sm[i*NN + j] + sm[j*NN + i])) + 1.0f;
    ah[((size_t)a*NN + i)*NN + j] = adj[i*NN + j] * m + ((i == j) ? 1.0f : 0.0f);
  }
}

__global__ void k_deg(const float* __restrict__ ah, float* __restrict__ invd) {
  int a = blockIdx.y, n = blockIdx.x;
  const float* A = ah + (size_t)a*NN*NN;
  __shared__ float sr[256], sc[256];
  int t = threadIdx.x;
  sr[t] = A[(size_t)n*NN + t] + A[(size_t)n*NN + t + 256];
  sc[t] = A[(size_t)t*NN + n] + A[(size_t)(t+256)*NN + n];
  __syncthreads();
  for (int s = 128; s > 0; s >>= 1) {
    if (t < s) { sr[t] += sr[t+s]; sc[t] += sc[t+s]; }
    __syncthreads();
  }
  if (t == 0) {
    float dr = sr[0], dc = sc[0];
    invd[(a*2 + 0)*NN + n] = dr > 0.f ? 1.f/dr : 0.f;
    invd[(a*2 + 1)*NN + n] = dc > 0.f ? 1.f/dc : 0.f;
  }
}

// ST[s][m][n]: s=2a+0: inv_dout[a][n]*ah[a][n][m] ; s=2a+1: inv_din[a][n]*ah[a][m][n]
__global__ void k_st(const float* __restrict__ ah, const float* __restrict__ invd,
                     float* __restrict__ ST) {
  int s = blockIdx.y, m = blockIdx.x;
  int a = s >> 1, dir = s & 1;
  const float* A = ah + (size_t)a*NN*NN;
  const float* inv = invd + (a*2 + dir)*NN;
  float* out = ST + ((size_t)s*NN + m)*NN;
  for (int n = threadIdx.x; n < NN; n += blockDim.x) {
    float v = dir ? A[(size_t)m*NN + n] : A[(size_t)n*NN + m];
    out[n] = inv[n] * v;
  }
}

// row sums of ST (once)
__global__ void k_srow(const float* __restrict__ ST, float* __restrict__ SRow) {
  int row = blockIdx.x;
  int t = threadIdx.x;
  __shared__ float red[256];
  red[t] = ST[(size_t)row*512 + t] + ST[(size_t)row*512 + t + 256];
  __syncthreads();
  for (int s = 128; s > 0; s >>= 1) {
    if (t < s) red[t] += red[t+s];
    __syncthreads();
  }
  if (t == 0) SRow[row] = red[0];
}

// fp16 split of ST with x256 scale
__global__ void k_splitA(const float* __restrict__ s, f16* __restrict__ a1,
                         f16* __restrict__ a2, int total) {
  int i = blockIdx.x*blockDim.x + threadIdx.x;
  if (i >= total) return;
  float v = s[i] * 256.0f;
  f16 hi = (f16)v;
  a1[i] = hi;
  a2[i] = (f16)(v - (float)hi);
}

// weight transpose + sum + x256 split: w [2l][4][128][O] -> wt [2l][2fb][O][128]
__global__ void k_wsumt(const float* __restrict__ w, f16* __restrict__ wt1,
                        f16* __restrict__ wt2, int O) {
  int idx = blockIdx.x*blockDim.x + threadIdx.x;
  int total = 2*2*O*128;
  if (idx >= total) return;
  int i  = idx & 127;
  int o  = (idx >> 7) % O;
  int fb = (idx / (128*O)) & 1;
  int l  = idx / (128*O*2);
  const float* wl = w + (((size_t)(l*4 + fb*2)*128 + i)*O + o);
  float v = (wl[0] + wl[(size_t)128*O]) * 256.0f;
  f16 hi = (f16)v;
  size_t dst = ((size_t)(l*2 + fb)*O + o)*128 + i;
  wt1[dst] = hi;
  wt2[dst] = (f16)(v - (float)hi);
}

// SX[n,b] for encoder step t
__global__ void k_sx(const float* __restrict__ x, const float* __restrict__ tm,
                     float* __restrict__ SX, int t) {
  int R = blockIdx.x*blockDim.x + threadIdx.x;   // 16384
  int b = R & 31, n = R >> 5;
  SX[R] = x[((size_t)b*TT + t)*NN + n] * (tanhf(tm[t*NN + n]) + 1.0f);
}

// PS[s,m][b] = sum_n ST[s,m][n] * SX[n,b]
__launch_bounds__(256)
__global__ void k_ps(const float* __restrict__ ST, const float* __restrict__ SX,
                     float* __restrict__ PS) {
  int row = blockIdx.x;                 // 2048
  int t = threadIdx.x;
  int b = t & 31, g = t >> 5;           // 8 n-groups
  const float* Sr = ST + (size_t)row*512 + g*64;
  const float* Sx = SX + (size_t)g*64*32 + b;
  float p = 0.f;
#pragma unroll
  for (int k = 0; k < 64; ++k) p = fmaf(Sr[k], Sx[(size_t)k*32], p);
  __shared__ float red[8][32];
  red[g][b] = p;
  __syncthreads();
  if (g == 0) {
    float s = 0.f;
#pragma unroll
    for (int q = 0; q < 8; ++q) s += red[q][b];
    PS[(size_t)row*32 + b] = s;
  }
}

// fill P x-part (cols 0..63): P[(sup)][(m,b)][u] = PS*fiw[u] + SRow*fib[u]
__global__ void k_pxfill(const float* __restrict__ PS, const float* __restrict__ SRow,
                         const float* __restrict__ fiw, const float* __restrict__ fib,
                         f16* __restrict__ P1, f16* __restrict__ P2) {
  int idx = blockIdx.x*blockDim.x + threadIdx.x;   // 4*16384*8
  int u8 = idx & 7;
  int R = (idx >> 3) & 16383;
  int sup = idx >> 17;
  int m = R >> 5, b = R & 31;
  float ps = PS[((size_t)sup*512 + m)*32 + b];
  float sr = SRow[(size_t)sup*512 + m];
  f16x8 h1, h2;
#pragma unroll
  for (int j = 0; j < 8; ++j) {
    int u = u8*8 + j;
    float v = ps*fiw[u] + sr*fib[u];
    f16 hi = (f16)v;
    h1[j] = hi;
    h2[j] = (f16)(v - (float)hi);
  }
  size_t dst = (size_t)sup*RRR*CC + (size_t)R*CC + u8*8;
  *(f16x8*)(P1 + dst) = h1;
  *(f16x8*)(P2 + dst) = h2;
}

// ---------- fused fp16-split MFMA GEMM: C = (A1B1 + A1B2 + A2B1)*scale ----------
// MODE 0: K1 l=1 full (512 blocks).  MODE 1: K3 (256 blocks, z=2).
// MODE 2: K1 l=0 h-part only (256 blocks, cols remapped to i in [64,128)).
template<int MODE>
__launch_bounds__(256)
__global__ void k_mm16f(const f16* __restrict__ A1g, const f16* __restrict__ A2g, long long aZ,
                        const f16* __restrict__ B1g, const f16* __restrict__ B2g, long long bZ,
                        f16* __restrict__ C1g, f16* __restrict__ C2g, int ldc, long long cZ,
                        float scale) {
  const int bid = blockIdx.x;
  const int c = bid & 7, i = bid >> 3;
  int x, y; long long z;
  if (MODE == 0)      { x = 2*c + (i & 1); y = i >> 1; z = 0; }
  else if (MODE == 1) { z = c >> 2; x = 2*(c & 3) + (i & 1); y = i >> 1; }
  else                { x = 2*c + (i & 1); y = i >> 1; z = 0; }
  const f16* A1 = A1g + z*aZ; const f16* A2 = A2g + z*aZ;
  const f16* B1 = B1g + z*bZ; const f16* B2 = B2g + z*bZ;
  f16* C1 = C1g + z*cZ; f16* C2 = C2g + z*cZ;
  const int row0 = x*128, col0 = y*128;

  __shared__ __align__(16) f16 As1[128*64], As2[128*64], Bs1[128*64], Bs2[128*64];
  const int tid = threadIdx.x;
  const int lane = tid & 63, w = tid >> 6;
  const int wr = w >> 1, wc = w & 1;
  const int rq = lane >> 3;
  const int gq = ((lane & 7) ^ rq) * 8;

  f32x4 acc[4][4];
#pragma unroll
  for (int m = 0; m < 4; ++m)
#pragma unroll
    for (int n = 0; n < 4; ++n) acc[m][n] = (f32x4){0.f,0.f,0.f,0.f};

  for (int k0 = 0; k0 < 512; k0 += 64) {
    __syncthreads();
#pragma unroll
    for (int q = 0; q < 4; ++q) {
      const int rloc = w*32 + q*8;
      gload16(A1 + (size_t)(row0 + rloc + rq)*512 + k0 + gq, As1 + rloc*64);
      gload16(A2 + (size_t)(row0 + rloc + rq)*512 + k0 + gq, As2 + rloc*64);
      gload16(B1 + (size_t)(col0 + rloc + rq)*512 + k0 + gq, Bs1 + rloc*64);
      gload16(B2 + (size_t)(col0 + rloc + rq)*512 + k0 + gq, Bs2 + rloc*64);
    }
    __syncthreads();
#pragma unroll
    for (int ks = 0; ks < 2; ++ks) {
      const int gk = ks*4 + (lane >> 4);
      f16x8 a1f[4], a2f[4], b1f[4], b2f[4];
#pragma unroll
      for (int m = 0; m < 4; ++m) {
        const int ra = wr*64 + m*16 + (lane & 15);
        const int sa = ra*64 + ((gk ^ (ra & 7))*8);
        a1f[m] = *(const f16x8*)(As1 + sa);
        a2f[m] = *(const f16x8*)(As2 + sa);
        const int rb = wc*64 + m*16 + (lane & 15);
        const int sb = rb*64 + ((gk ^ (rb & 7))*8);
        b1f[m] = *(const f16x8*)(Bs1 + sb);
        b2f[m] = *(const f16x8*)(Bs2 + sb);
      }
#pragma unroll
      for (int m = 0; m < 4; ++m)
#pragma unroll
        for (int n = 0; n < 4; ++n) {
          acc[m][n] = __builtin_amdgcn_mfma_f32_16x16x32_f16(a1f[m], b1f[n], acc[m][n], 0, 0, 0);
          acc[m][n] = __builtin_amdgcn_mfma_f32_16x16x32_f16(a1f[m], b2f[n], acc[m][n], 0, 0, 0);
          acc[m][n] = __builtin_amdgcn_mfma_f32_16x16x32_f16(a2f[m], b1f[n], acc[m][n], 0, 0, 0);
        }
    }
  }
#pragma unroll
  for (int m = 0; m < 4; ++m) {
    const int row = row0 + wr*64 + m*16 + (lane >> 4)*4;
#pragma unroll
    for (int n = 0; n < 4; ++n) {
      const int rest = n*16 + (lane & 15);
      int col;
      if (MODE == 2) col = col0*2 + wc*128 + 64 + rest;   // remap to h-part cols
      else           col = col0 + wc*64 + rest;
#pragma unroll
      for (int r = 0; r < 4; ++r) {
        float v = acc[m][n][r] * scale;
        f16 hi = (f16)v;
        C1[(size_t)(row + r)*ldc + col] = hi;
        C2[(size_t)(row + r)*ldc + col] = (f16)(v - (float)hi);
      }
    }
  }
}

// ---------- gates MFMA: sigmoid epilogue; writes u_g f32 and RHT (transposed f16 split) ----------
__launch_bounds__(256)
__global__ void k_gatesmf(const f16* __restrict__ P1, const f16* __restrict__ P2,
                          const f16* __restrict__ W1g0, const f16* __restrict__ W2g0,
                          const f16* __restrict__ W1g1, const f16* __restrict__ W2g1,
                          const float* __restrict__ b0, const float* __restrict__ b1,
                          const float* __restrict__ h,
                          f16* __restrict__ RHT1, f16* __restrict__ RHT2,
                          float* __restrict__ ubuf) {
  const int g = blockIdx.z;
  const f16* W1 = g ? W1g1 : W1g0;
  const f16* W2 = g ? W2g1 : W2g0;
  const float* bias = g ? b1 : b0;
  f16* RHT1g = RHT1 + (size_t)g*2048*512;
  f16* RHT2g = RHT2 + (size_t)g*2048*512;
  float* u_g  = ubuf + (size_t)g * RRR * UU;
  __shared__ __align__(16) f16 smem[4*128*64];
  f16* As1 = smem;          f16* As2 = smem + 8192;
  f16* Bs1 = smem + 16384;  f16* Bs2 = smem + 24576;
  const int tid = threadIdx.x;
  const int lane = tid & 63, w = tid >> 6;
  const int wr = w >> 1, wc = w & 1;
  const int R0 = blockIdx.x * 128;
  const int rq = lane >> 3;
  const int gq = ((lane & 7) ^ rq) * 8;

  f32x4 acc[4][4];
#pragma unroll
  for (int m = 0; m < 4; ++m)
#pragma unroll
    for (int n = 0; n < 4; ++n) acc[m][n] = (f32x4){0.f,0.f,0.f,0.f};

  for (int sup = 0; sup < 2; ++sup) {
    const f16* A1 = P1 + (size_t)(2*g + sup)*RRR*CC;
    const f16* A2 = P2 + (size_t)(2*g + sup)*RRR*CC;
    const f16* B1 = W1 + (size_t)sup*16384;
    const f16* B2 = W2 + (size_t)sup*16384;
    for (int k0 = 0; k0 < 128; k0 += 64) {
      __syncthreads();
#pragma unroll
      for (int q = 0; q < 4; ++q) {
        const int rloc = w*32 + q*8;
        gload16(A1 + (size_t)(R0 + rloc + rq)*128 + k0 + gq, As1 + rloc*64);
        gload16(A2 + (size_t)(R0 + rloc + rq)*128 + k0 + gq, As2 + rloc*64);
        gload16(B1 + (size_t)(rloc + rq)*128 + k0 + gq, Bs1 + rloc*64);
        gload16(B2 + (size_t)(rloc + rq)*128 + k0 + gq, Bs2 + rloc*64);
      }
      __syncthreads();
#pragma unroll
      for (int ks = 0; ks < 2; ++ks) {
        const int gk = ks*4 + (lane >> 4);
        f16x8 a1f[4], a2f[4], b1f[4], b2f[4];
#pragma unroll
        for (int m = 0; m < 4; ++m) {
          const int ra = wr*64 + m*16 + (lane & 15);
          const int sa = ra*64 + ((gk ^ (ra & 7))*8);
          a1f[m] = *(const f16x8*)(As1 + sa);
          a2f[m] = *(const f16x8*)(As2 + sa);
          const int rb = wc*64 + m*16 + (lane & 15);
          const int sb = rb*64 + ((gk ^ (rb & 7))*8);
          b1f[m] = *(const f16x8*)(Bs1 + sb);
          b2f[m] = *(const f16x8*)(Bs2 + sb);
        }
#pragma unroll
        for (int m = 0; m < 4; ++m)
#pragma unroll
          for (int n = 0; n < 4; ++n) {
            acc[m][n] = __builtin_amdgcn_mfma_f32_16x16x32_f16(a1f[m], b1f[n], acc[m][n], 0, 0, 0);
            acc[m][n] = __builtin_amdgcn_mfma_f32_16x16x32_f16(a1f[m], b2f[n], acc[m][n], 0, 0, 0);
            acc[m][n] = __builtin_amdgcn_mfma_f32_16x16x32_f16(a2f[m], b1f[n], acc[m][n], 0, 0, 0);
          }
      }
    }
  }
  __syncthreads();                       // all LDS reads done; reuse As region
  float* rhst = (float*)smem;            // [128][64] f32 = 32 KB
#pragma unroll
  for (int m = 0; m < 4; ++m) {
    const int row = R0 + wr*64 + m*16 + (lane >> 4)*4;
#pragma unroll
    for (int n = 0; n < 4; ++n) {
      const int o = wc*64 + n*16 + (lane & 15);
#pragma unroll
      for (int r = 0; r < 4; ++r) {
        const int R = row + r;
        float v = acc[m][n][r] * 0.00390625f + bias[o];
        float sg = 1.f / (1.f + expf(-v));
        if (o < 64) rhst[(R - R0)*64 + o] = sg * h[(size_t)R*UU + o];
        else        u_g[(size_t)R*UU + o - 64] = sg;
      }
    }
  }
  __syncthreads();
  const int n0 = blockIdx.x * 4;         // node base (block covers 4 nodes)
#pragma unroll
  for (int it = 0; it < 8; ++it) {
    const int row = tid + it*256;        // (b*64+u)
    const int b = row >> 6, u = row & 63;
    f16x4 h1v, h2v;
#pragma unroll
    for (int nn = 0; nn < 4; ++nn) {
      float v = rhst[(nn*32 + b)*64 + u];
      f16 hi = (f16)v;
      h1v[nn] = hi;
      h2v[nn] = (f16)(v - (float)hi);
    }
    *(f16x4*)(RHT1g + (size_t)row*512 + n0) = h1v;
    *(f16x4*)(RHT2g + (size_t)row*512 + n0) = h2v;
  }
}

// ---------- candidate (both gates) + GRU update; writes h f32 + transposed-split h ----------
__launch_bounds__(256)
__global__ void k_candupd(const f16* __restrict__ P1, const f16* __restrict__ P2,
                          const f16* __restrict__ Q1, const f16* __restrict__ Q2,
                          const f16* __restrict__ Wc1g0, const f16* __restrict__ Wc2g0,
                          const f16* __restrict__ Wc1g1, const f16* __restrict__ Wc2g1,
                          const float* __restrict__ b0, const float* __restrict__ b1,
                          const float* __restrict__ ubuf,
                          float* __restrict__ h, int lmode,
                          f16* __restrict__ HT01, f16* __restrict__ HT02,
                          f16* __restrict__ XT1, f16* __restrict__ XT2) {
  __shared__ __align__(16) f16 smem[4*64*64];
  f16* As1 = smem;         f16* As2 = smem + 4096;
  f16* Bs1 = smem + 8192;  f16* Bs2 = smem + 12288;
  const int tid = threadIdx.x;
  const int lane = tid & 63, w = tid >> 6;
  const int R0 = blockIdx.x * 64;
  const int rq = lane >> 3;
  const int gq = ((lane & 7) ^ rq) * 8;

  f32x4 acc[2][4];
#pragma unroll
  for (int g = 0; g < 2; ++g)
#pragma unroll
    for (int n = 0; n < 4; ++n) acc[g][n] = (f32x4){0.f,0.f,0.f,0.f};

#pragma unroll
  for (int g = 0; g < 2; ++g) {
    const f16* W1 = g ? Wc1g1 : Wc1g0;
    const f16* W2 = g ? Wc2g1 : Wc2g0;
#pragma unroll
    for (int seg = 0; seg < 4; ++seg) {
      const int sup = seg >> 1, isQ = seg & 1;
      const f16* A1 = isQ ? (Q1 + ((size_t)g*2 + sup)*1048576)
                          : (P1 + (size_t)(2*g + sup)*RRR*CC);
      const f16* A2 = isQ ? (Q2 + ((size_t)g*2 + sup)*1048576)
                          : (P2 + (size_t)(2*g + sup)*RRR*CC);
      const int lda = isQ ? 64 : 128;
      const f16* B1 = W1 + (size_t)sup*8192 + (isQ ? 64 : 0);
      const f16* B2 = W2 + (size_t)sup*8192 + (isQ ? 64 : 0);
      __syncthreads();
#pragma unroll
      for (int q = 0; q < 1; ++q) {
        const int rloc = w*16 + q*8;
        gload16(A1 + (size_t)(R0 + rloc + rq)*lda + gq, As1 + rloc*64);
        gload16(A2 + (size_t)(R0 + rloc + rq)*lda + gq, As2 + rloc*64);
        gload16(B1 + (size_t)(rloc + rq)*128 + gq, Bs1 + rloc*64);
        gload16(B2 + (size_t)(rloc + rq)*128 + gq, Bs2 + rloc*64);
      }
#pragma unroll
      for (int q = 1; q < 2; ++q) {
        const int rloc = w*16 + q*8;
        gload16(A1 + (size_t)(R0 + rloc + rq)*lda + gq, As1 + rloc*64);
        gload16(A2 + (size_t)(R0 + rloc + rq)*lda + gq, As2 + rloc*64);
        gload16(B1 + (size_t)(rloc + rq)*128 + gq, Bs1 + rloc*64);
        gload16(B2 + (size_t)(rloc + rq)*128 + gq, Bs2 + rloc*64);
      }
      __syncthreads();
#pragma unroll
      for (int ks = 0; ks < 2; ++ks) {
        const int gk = ks*4 + (lane >> 4);
        const int ra = w*16 + (lane & 15);
        const int sa = ra*64 + ((gk ^ (ra & 7))*8);
        f16x8 a1f = *(const f16x8*)(As1 + sa);
        f16x8 a2f = *(const f16x8*)(As2 + sa);
        f16x8 b1f[4], b2f[4];
#pragma unroll
        for (int n = 0; n < 4; ++n) {
          const int rb = n*16 + (lane & 15);
          const int sb = rb*64 + ((gk ^ (rb & 7))*8);
          b1f[n] = *(const f16x8*)(Bs1 + sb);
          b2f[n] = *(const f16x8*)(Bs2 + sb);
        }
#pragma unroll
        for (int n = 0; n < 4; ++n) {
          acc[g][n] = __builtin_amdgcn_mfma_f32_16x16x32_f16(a1f, b1f[n], acc[g][n], 0, 0, 0);
          acc[g][n] = __builtin_amdgcn_mfma_f32_16x16x32_f16(a1f, b2f[n], acc[g][n], 0, 0, 0);
          acc[g][n] = __builtin_amdgcn_mfma_f32_16x16x32_f16(a2f, b1f[n], acc[g][n], 0, 0, 0);
        }
      }
    }
  }
  __syncthreads();                       // LDS reads done; reuse As region
  float* hnst = (float*)smem;            // [64][64] f32 = 16 KB
#pragma unroll
  for (int n = 0; n < 4; ++n) {
    const int o = n*16 + (lane & 15);
#pragma unroll
    for (int r = 0; r < 4; ++r) {
      const int RR = w*16 + (lane >> 4)*4 + r;
      const int R = R0 + RR;
      const size_t idx = (size_t)R*UU + o;
      float c1 = tanhf(acc[0][n][r] * 0.00390625f + b0[o]);
      float c2 = tanhf(acc[1][n][r] * 0.00390625f + b1[o]);
      float u = 0.5f*(ubuf[idx] + ubuf[(size_t)RRR*UU + idx]);
      float cc = 0.5f*(c1 + c2);
      float hn = (1.f - u)*h[idx] + u*cc;
      h[idx] = hn;
      hnst[RR*64 + o] = hn;
    }
  }
  __syncthreads();
  const int n0 = blockIdx.x * 2;         // node base (block covers 2 nodes)
#pragma unroll
  for (int it = 0; it < 8; ++it) {
    const int row = tid + it*256;        // (b*64+o), 2048 rows
    const int b = row >> 6, o = row & 63;
    float v0 = hnst[(0*32 + b)*64 + o];
    float v1 = hnst[(1*32 + b)*64 + o];
    f16 hi0 = (f16)v0, hi1 = (f16)v1;
    f16 lo0 = (f16)(v0 - (float)hi0), lo1 = (f16)(v1 - (float)hi1);
    f16x2 hv; hv[0] = hi0; hv[1] = hi1;
    f16x2 lv; lv[0] = lo0; lv[1] = lo1;
    if (lmode == 0) {
      *(f16x2*)(HT01 + (size_t)(b*64 + o)*512 + n0) = hv;
      *(f16x2*)(HT02 + (size_t)(b*64 + o)*512 + n0) = lv;
      *(f16x2*)(XT1 + (size_t)(b*128 + o)*512 + n0) = hv;
      *(f16x2*)(XT2 + (size_t)(b*128 + o)*512 + n0) = lv;
    } else {
      *(f16x2*)(XT1 + (size_t)(b*128 + 64 + o)*512 + n0) = hv;
      *(f16x2*)(XT2 + (size_t)(b*128 + 64 + o)*512 + n0) = lv;
    }
  }
}

// ---------- decoder output + next SX ----------
__global__ void k_out(const float* __restrict__ h1, const float* __restrict__ fow,
                      const float* __restrict__ fob, float* __restrict__ out,
                      float* __restrict__ SX, int p) {
  int R = blockIdx.x*blockDim.x + threadIdx.x;   // 16384
  int b = R & 31, n = R >> 5;
  const float* hr = h1 + (size_t)R*UU;
  float s = fob[0];
#pragma unroll
  for (int u = 0; u < UU; ++u) s = fmaf(hr[u], fow[u], s);
  out[(size_t)b*(NP*NN) + (size_t)p*NN + n] = s;
  SX[R] = s;
}

extern "C" void kernel_launch(void* const* d_in, const int* in_sizes, int n_in,
                              void* d_out, int out_size, void* d_ws, size_t ws_size,
                              hipStream_t stream) {
  (void)in_sizes; (void)n_in; (void)out_size; (void)ws_size;
  const float* x   = (const float*)d_in[0];
  const float* adj = (const float*)d_in[1];
  const float* sm1 = (const float*)d_in[2];
  const float* sm2 = (const float*)d_in[3];
  const float* tm  = (const float*)d_in[4];
  const float* fiw = (const float*)d_in[5];
  const float* fib = (const float*)d_in[6];
  const float* fow = (const float*)d_in[7];
  const float* fob = (const float*)d_in[8];

  float* WS   = (float*)d_ws;
  float* ST   = WS + OFF_ST;
  float* AH   = WS + OFF_AH;
  float* INVD = WS + OFF_INVD;
  float* H    = WS + OFF_H;
  float* Ubuf = WS + OFF_U;
  float* SX   = WS + OFF_SX;
  float* PS   = WS + OFF_PS;
  float* SRow = WS + OFF_SROW;
  f16* HT01 = (f16*)(WS + OFF_HT0);
  f16* HT02 = (f16*)(WS + OFF_HT0 + 524288);
  f16* ST1  = (f16*)(WS + OFF_ST16A);
  f16* ST2  = (f16*)(WS + OFF_ST16B);
  f16* XHT1 = (f16*)(WS + OFF_XHT1);
  f16* XHT2 = (f16*)(WS + OFF_XHT2);
  f16* RHT1 = (f16*)(WS + OFF_RHT1);
  f16* RHT2 = (f16*)(WS + OFF_RHT2);
  f16* P1   = (f16*)(WS + OFF_P1);
  f16* P2   = (f16*)(WS + OFF_P2);
  f16* Q1   = (f16*)(WS + OFF_Q1);
  f16* Q2   = (f16*)(WS + OFF_Q2);
  f16* WT1  = (f16*)(WS + OFF_WT1);
  f16* WT2  = (f16*)(WS + OFF_WT2);

  // ---- supports ----
  k_build_ah<<<dim3(512,2),256,0,stream>>>(adj, sm1, sm2, AH);
  k_deg<<<dim3(512,2),256,0,stream>>>(AH, INVD);
  k_st<<<dim3(512,4),256,0,stream>>>(AH, INVD, ST);
  k_splitA<<<4096,256,0,stream>>>(ST, ST1, ST2, 2048*512);
  k_srow<<<2048,256,0,stream>>>(ST, SRow);

  // ---- weight transposed split sums ----
  const int widx[8] = {9, 11, 13, 15, 17, 19, 21, 23};
  const int Osz[8]  = {128, 64, 128, 64, 128, 64, 128, 64};
  const size_t woff16[8] = {0, 65536, 98304, 163840, 196608, 262144, 294912, 360448};
  for (int tau = 0; tau < 8; ++tau) {
    int total = 2*2*Osz[tau]*128;
    k_wsumt<<<(total + 255)/256, 256, 0, stream>>>((const float*)d_in[widx[tau]],
                                                   WT1 + woff16[tau], WT2 + woff16[tau],
                                                   Osz[tau]);
  }

  // h = 0 initial state (f32 and transposed f16 copies)
  hipMemsetAsync(H,    0, (size_t)2*RRR*UU*sizeof(float), stream);
  hipMemsetAsync(HT01, 0, (size_t)2048*512*sizeof(f16), stream);
  hipMemsetAsync(HT02, 0, (size_t)2048*512*sizeof(f16), stream);
  hipMemsetAsync(XHT1, 0, (size_t)4096*512*sizeof(f16), stream);
  hipMemsetAsync(XHT2, 0, (size_t)4096*512*sizeof(f16), stream);

  const float inv256 = 1.0f/256.0f;

  for (int step = 0; step < TT + NP; ++step) {
    const bool enc = step < TT;
    const int ph = enc ? 0 : 1;
    if (enc)             k_sx<<<64,256,0,stream>>>(x, tm, SX, step);
    else if (step == TT) hipMemsetAsync(SX, 0, 16384*sizeof(float), stream);
    // decoder steps > TT: k_out of previous step wrote SX

    k_ps<<<2048,256,0,stream>>>(ST, SX, PS);

    for (int l = 0; l < 2; ++l) {
      float* h_l  = H  + (size_t)l*RRR*UU;
      const size_t lru = (size_t)l*2*128*128;
      const size_t lc  = (size_t)l*2*64*128;
      const f16* Wru1a = WT1 + woff16[ph*4+0] + lru;
      const f16* Wru2a = WT2 + woff16[ph*4+0] + lru;
      const f16* Wru1b = WT1 + woff16[ph*4+2] + lru;
      const f16* Wru2b = WT2 + woff16[ph*4+2] + lru;
      const f16* Wc1a  = WT1 + woff16[ph*4+1] + lc;
      const f16* Wc2a  = WT2 + woff16[ph*4+1] + lc;
      const f16* Wc1b  = WT1 + woff16[ph*4+3] + lc;
      const f16* Wc2b  = WT2 + woff16[ph*4+3] + lc;
      const float* bru  = (const float*)d_in[enc?10:18] + (size_t)l*128;
      const float* bc   = (const float*)d_in[enc?12:20] + (size_t)l*64;
      const float* bru2 = (const float*)d_in[enc?14:22] + (size_t)l*128;
      const float* bc2  = (const float*)d_in[enc?16:24] + (size_t)l*64;

      if (l == 0) {
        // K1 h-part GEMM from HT0 (cols i in [64,128))
        k_mm16f<2><<<256,256,0,stream>>>(ST1, ST2, 0, HT01, HT02, 0,
                                         P1, P2, 4096, 0, inv256);
        // K1 x-part rank-1 fill (cols i in [0,64))
        k_pxfill<<<2048,256,0,stream>>>(PS, SRow, fiw, fib, P1, P2);
      } else {
        // K1 full GEMM from XHT
        k_mm16f<0><<<512,256,0,stream>>>(ST1, ST2, 0, XHT1, XHT2, 0,
                                         P1, P2, 4096, 0, inv256);
      }
      // K2: gates -> RHT (transposed split), Ubuf
      k_gatesmf<<<dim3(128,1,2),256,0,stream>>>(P1, P2, Wru1a, Wru2a, Wru1b, Wru2b,
                                                bru, bru2, h_l, RHT1, RHT2, Ubuf);
      // K3: Q per gate from RHT
      k_mm16f<1><<<256,256,0,stream>>>(ST1, ST2, (long long)1024*512,
                                       RHT1, RHT2, (long long)2048*512,
                                       Q1, Q2, 2048, (long long)1024*2048, inv256);
      // K4: candidates + GRU update (+ transposed-split h maintenance)
      k_candupd<<<256,256,0,stream>>>(P1, P2, Q1, Q2, Wc1a, Wc2a, Wc1b, Wc2b,
                                      bc, bc2, Ubuf, h_l, l,
                                      HT01, HT02, XHT1, XHT2);
    }
    if (!enc) {
      int p = step - TT;
      k_out<<<64,256,0,stream>>>(H + (size_t)RRR*UU, fow, fob,
                                 (float*)d_out, SX, p);
    }
  }
}

// Round 9
// 5383.425 us; speedup vs baseline: 1.1169x; 1.1169x over previous
//
#include <hip/hip_runtime.h>
#include <math.h>

#define NN 512
#define BB 32
#define UU 64
#define CC 128
#define TT 12
#define NP 12
#define RRR (NN*BB)   // 16384 rows = (n,b)

typedef _Float16 f16;
typedef f16 f16x8 __attribute__((ext_vector_type(8)));
typedef f16 f16x4 __attribute__((ext_vector_type(4)));
typedef float f32x4 __attribute__((ext_vector_type(4)));

// direct global->LDS DMA, 16B per lane; dst wave-uniform base (lane*16 added by HW)
__device__ __forceinline__ void gload16(const f16* g, f16* l) {
  __builtin_amdgcn_global_load_lds((const __attribute__((address_space(1))) void*)g,
                                   (__attribute__((address_space(3))) void*)l, 16, 0, 0);
}

// ---- workspace layout (float units) ----
static const size_t OFF_ST    = 0;                              // [4][512][512] f32
static const size_t OFF_AH    = OFF_ST   + (size_t)4*512*512;
static const size_t OFF_INVD  = OFF_AH   + (size_t)2*512*512;
static const size_t OFF_XH    = OFF_INVD + 2048;                // [2][16384][128] f32
static const size_t OFF_H     = OFF_XH   + (size_t)2*RRR*CC;    // [2][16384][64] f32
static const size_t OFF_RH    = OFF_H    + (size_t)2*RRR*UU;    // [2][16384][64] f32
static const size_t OFF_U     = OFF_RH   + (size_t)2*RRR*UU;
static const size_t OFF_SX    = OFF_U    + (size_t)2*RRR*UU;    // 16384 f32
static const size_t OFF_PS    = OFF_SX   + 16384;               // 4*512*32 f32
static const size_t OFF_SROW  = OFF_PS   + 65536;               // 2048 f32
static const size_t OFF_F16   = OFF_SROW + 2048;
// f16 regions (float units = f16count/2)
static const size_t OFF_ST16A = OFF_F16;                        // 2048*512 f16
static const size_t OFF_ST16B = OFF_ST16A + 524288;
static const size_t OFF_XHT1  = OFF_ST16B + 524288;             // 4096*512 f16
static const size_t OFF_XHT2  = OFF_XHT1  + 1048576;
static const size_t OFF_RHT1  = OFF_XHT2  + 1048576;            // 2*2048*512 f16
static const size_t OFF_RHT2  = OFF_RHT1  + 1048576;
static const size_t OFF_P1    = OFF_RHT2  + 1048576;            // 2048*4096 f16
static const size_t OFF_P2    = OFF_P1    + 4194304;
static const size_t OFF_Q1    = OFF_P2    + 4194304;            // 4*512*2048 f16
static const size_t OFF_Q2    = OFF_Q1    + 2097152;
static const size_t OFF_WT1   = OFF_Q2    + 2097152;            // 393216 f16
static const size_t OFF_WT2   = OFF_WT1   + 196608;

// ---------- precompute ----------
__global__ void k_build_ah(const float* __restrict__ adj, const float* __restrict__ sm1,
                           const float* __restrict__ sm2, float* __restrict__ ah) {
  int a = blockIdx.y, i = blockIdx.x;
  const float* sm = a ? sm2 : sm1;
  for (int j = threadIdx.x; j < NN; j += blockDim.x) {
    float m = tanhf(0.5f * (sm[i*NN + j] + sm[j*NN + i])) + 1.0f;
    ah[((size_t)a*NN + i)*NN + j] = adj[i*NN + j] * m + ((i == j) ? 1.0f : 0.0f);
  }
}

__global__ void k_deg(const float* __restrict__ ah, float* __restrict__ invd) {
  int a = blockIdx.y, n = blockIdx.x;
  const float* A = ah + (size_t)a*NN*NN;
  __shared__ float sr[256], sc[256];
  int t = threadIdx.x;
  sr[t] = A[(size_t)n*NN + t] + A[(size_t)n*NN + t + 256];
  sc[t] = A[(size_t)t*NN + n] + A[(size_t)(t+256)*NN + n];
  __syncthreads();
  for (int s = 128; s > 0; s >>= 1) {
    if (t < s) { sr[t] += sr[t+s]; sc[t] += sc[t+s]; }
    __syncthreads();
  }
  if (t == 0) {
    float dr = sr[0], dc = sc[0];
    invd[(a*2 + 0)*NN + n] = dr > 0.f ? 1.f/dr : 0.f;
    invd[(a*2 + 1)*NN + n] = dc > 0.f ? 1.f/dc : 0.f;
  }
}

// ST[s][m][n]: s=2a+0: inv_dout[a][n]*ah[a][n][m] ; s=2a+1: inv_din[a][n]*ah[a][m][n]
__global__ void k_st(const float* __restrict__ ah, const float* __restrict__ invd,
                     float* __restrict__ ST) {
  int s = blockIdx.y, m = blockIdx.x;
  int a = s >> 1, dir = s & 1;
  const float* A = ah + (size_t)a*NN*NN;
  const float* inv = invd + (a*2 + dir)*NN;
  float* out = ST + ((size_t)s*NN + m)*NN;
  for (int n = threadIdx.x; n < NN; n += blockDim.x) {
    float v = dir ? A[(size_t)m*NN + n] : A[(size_t)n*NN + m];
    out[n] = inv[n] * v;
  }
}

// row sums of ST (once)
__global__ void k_srow(const float* __restrict__ ST, float* __restrict__ SRow) {
  int row = blockIdx.x;
  int t = threadIdx.x;
  __shared__ float red[256];
  red[t] = ST[(size_t)row*512 + t] + ST[(size_t)row*512 + t + 256];
  __syncthreads();
  for (int s = 128; s > 0; s >>= 1) {
    if (t < s) red[t] += red[t+s];
    __syncthreads();
  }
  if (t == 0) SRow[row] = red[0];
}

// fp16 split of ST with x256 scale
__global__ void k_splitA(const float* __restrict__ s, f16* __restrict__ a1,
                         f16* __restrict__ a2, int total) {
  int i = blockIdx.x*blockDim.x + threadIdx.x;
  if (i >= total) return;
  float v = s[i] * 256.0f;
  f16 hi = (f16)v;
  a1[i] = hi;
  a2[i] = (f16)(v - (float)hi);
}

// weight transpose + sum + x256 split: w [2l][4][128][O] -> wt [2l][2fb][O][128]
__global__ void k_wsumt(const float* __restrict__ w, f16* __restrict__ wt1,
                        f16* __restrict__ wt2, int O) {
  int idx = blockIdx.x*blockDim.x + threadIdx.x;
  int total = 2*2*O*128;
  if (idx >= total) return;
  int i  = idx & 127;
  int o  = (idx >> 7) % O;
  int fb = (idx / (128*O)) & 1;
  int l  = idx / (128*O*2);
  const float* wl = w + (((size_t)(l*4 + fb*2)*128 + i)*O + o);
  float v = (wl[0] + wl[(size_t)128*O]) * 256.0f;
  f16 hi = (f16)v;
  size_t dst = ((size_t)(l*2 + fb)*O + o)*128 + i;
  wt1[dst] = hi;
  wt2[dst] = (f16)(v - (float)hi);
}

// SX[n,b] for encoder step t
__global__ void k_sx(const float* __restrict__ x, const float* __restrict__ tm,
                     float* __restrict__ SX, int t) {
  int R = blockIdx.x*blockDim.x + threadIdx.x;   // 16384
  int b = R & 31, n = R >> 5;
  SX[R] = x[((size_t)b*TT + t)*NN + n] * (tanhf(tm[t*NN + n]) + 1.0f);
}

// PS[s,m][b] = sum_n ST[s,m][n] * SX[n,b]
__launch_bounds__(256)
__global__ void k_ps(const float* __restrict__ ST, const float* __restrict__ SX,
                     float* __restrict__ PS) {
  int row = blockIdx.x;                 // 2048
  int t = threadIdx.x;
  int b = t & 31, g = t >> 5;           // 8 n-groups
  const float* Sr = ST + (size_t)row*512 + g*64;
  const float* Sx = SX + (size_t)g*64*32 + b;
  float p = 0.f;
#pragma unroll
  for (int k = 0; k < 64; ++k) p = fmaf(Sr[k], Sx[(size_t)k*32], p);
  __shared__ float red[8][32];
  red[g][b] = p;
  __syncthreads();
  if (g == 0) {
    float s = 0.f;
#pragma unroll
    for (int q = 0; q < 8; ++q) s += red[q][b];
    PS[(size_t)row*32 + b] = s;
  }
}

// fill P x-part (cols 0..63): P[(sup)][(m,b)][u] = PS*fiw[u] + SRow*fib[u]
__global__ void k_pxfill(const float* __restrict__ PS, const float* __restrict__ SRow,
                         const float* __restrict__ fiw, const float* __restrict__ fib,
                         f16* __restrict__ P1, f16* __restrict__ P2) {
  int idx = blockIdx.x*blockDim.x + threadIdx.x;   // 4*16384*8
  int u8 = idx & 7;
  int R = (idx >> 3) & 16383;
  int sup = idx >> 17;
  int m = R >> 5, b = R & 31;
  float ps = PS[((size_t)sup*512 + m)*32 + b];
  float sr = SRow[(size_t)sup*512 + m];
  f16x8 h1, h2;
#pragma unroll
  for (int j = 0; j < 8; ++j) {
    int u = u8*8 + j;
    float v = ps*fiw[u] + sr*fib[u];
    f16 hi = (f16)v;
    h1[j] = hi;
    h2[j] = (f16)(v - (float)hi);
  }
  size_t dst = (size_t)sup*RRR*CC + (size_t)R*CC + u8*8;
  *(f16x8*)(P1 + dst) = h1;
  *(f16x8*)(P2 + dst) = h2;
}

// transpose + fp16-split: src f32 [512 x lds_], dst f16 [cols x 512]
__launch_bounds__(256)
__global__ void k_tsplit(const float* __restrict__ src, int lds_, long long srcZ,
                         f16* __restrict__ d1, f16* __restrict__ d2, long long dstZ) {
  __shared__ float tile[64][65];
  const float* S = src + (size_t)blockIdx.z*srcZ;
  f16* D1 = d1 + (size_t)blockIdx.z*dstZ;
  f16* D2 = d2 + (size_t)blockIdx.z*dstZ;
  int t = threadIdx.x;
  int c0 = blockIdx.x*64, k0 = blockIdx.y*64;
#pragma unroll
  for (int it = 0; it < 4; ++it) {
    int r = (t >> 4) + it*16;
    int c = (t & 15)*4;
    float4 v = *(const float4*)(S + (size_t)(k0 + r)*lds_ + c0 + c);
    tile[r][c] = v.x; tile[r][c+1] = v.y; tile[r][c+2] = v.z; tile[r][c+3] = v.w;
  }
  __syncthreads();
#pragma unroll
  for (int it = 0; it < 4; ++it) {
    int c = (t >> 4) + it*16;       // dst row (source col)
    int ks = (t & 15)*4;
    f16x4 h1, h2;
#pragma unroll
    for (int j = 0; j < 4; ++j) {
      float v = tile[ks + j][c];
      f16 hi = (f16)v;
      h1[j] = hi;
      h2[j] = (f16)(v - (float)hi);
    }
    *(f16x4*)(D1 + (size_t)(c0 + c)*512 + k0 + ks) = h1;
    *(f16x4*)(D2 + (size_t)(c0 + c)*512 + k0 + ks) = h2;
  }
}

// ---------- fused fp16-split MFMA GEMM: C = (A1B1 + A1B2 + A2B1)*scale ----------
// MODE 0: K1 l=1 full (512 blocks).  MODE 1: K3 (256 blocks, z=2).
// MODE 2: K1 l=0 h-part only (256 blocks, cols remapped to i in [64,128)).
template<int MODE>
__launch_bounds__(256)
__global__ void k_mm16f(const f16* __restrict__ A1g, const f16* __restrict__ A2g, long long aZ,
                        const f16* __restrict__ B1g, const f16* __restrict__ B2g, long long bZ,
                        f16* __restrict__ C1g, f16* __restrict__ C2g, int ldc, long long cZ,
                        float scale) {
  const int bid = blockIdx.x;
  const int c = bid & 7, i = bid >> 3;
  int x, y; long long z;
  if (MODE == 0)      { x = 2*c + (i & 1); y = i >> 1; z = 0; }
  else if (MODE == 1) { z = c >> 2; x = 2*(c & 3) + (i & 1); y = i >> 1; }
  else                { x = 2*c + (i & 1); y = i >> 1; z = 0; }
  const f16* A1 = A1g + z*aZ; const f16* A2 = A2g + z*aZ;
  const f16* B1 = B1g + z*bZ; const f16* B2 = B2g + z*bZ;
  f16* C1 = C1g + z*cZ; f16* C2 = C2g + z*cZ;
  const int row0 = x*128, col0 = y*128;

  __shared__ __align__(16) f16 As1[128*64], As2[128*64], Bs1[128*64], Bs2[128*64];
  const int tid = threadIdx.x;
  const int lane = tid & 63, w = tid >> 6;
  const int wr = w >> 1, wc = w & 1;
  const int rq = lane >> 3;
  const int gq = ((lane & 7) ^ rq) * 8;

  f32x4 acc[4][4];
#pragma unroll
  for (int m = 0; m < 4; ++m)
#pragma unroll
    for (int n = 0; n < 4; ++n) acc[m][n] = (f32x4){0.f,0.f,0.f,0.f};

  for (int k0 = 0; k0 < 512; k0 += 64) {
    __syncthreads();
#pragma unroll
    for (int q = 0; q < 4; ++q) {
      const int rloc = w*32 + q*8;
      gload16(A1 + (size_t)(row0 + rloc + rq)*512 + k0 + gq, As1 + rloc*64);
      gload16(A2 + (size_t)(row0 + rloc + rq)*512 + k0 + gq, As2 + rloc*64);
      gload16(B1 + (size_t)(col0 + rloc + rq)*512 + k0 + gq, Bs1 + rloc*64);
      gload16(B2 + (size_t)(col0 + rloc + rq)*512 + k0 + gq, Bs2 + rloc*64);
    }
    __syncthreads();
#pragma unroll
    for (int ks = 0; ks < 2; ++ks) {
      const int gk = ks*4 + (lane >> 4);
      f16x8 a1f[4], a2f[4], b1f[4], b2f[4];
#pragma unroll
      for (int m = 0; m < 4; ++m) {
        const int ra = wr*64 + m*16 + (lane & 15);
        const int sa = ra*64 + ((gk ^ (ra & 7))*8);
        a1f[m] = *(const f16x8*)(As1 + sa);
        a2f[m] = *(const f16x8*)(As2 + sa);
        const int rb = wc*64 + m*16 + (lane & 15);
        const int sb = rb*64 + ((gk ^ (rb & 7))*8);
        b1f[m] = *(const f16x8*)(Bs1 + sb);
        b2f[m] = *(const f16x8*)(Bs2 + sb);
      }
#pragma unroll
      for (int m = 0; m < 4; ++m)
#pragma unroll
        for (int n = 0; n < 4; ++n) {
          acc[m][n] = __builtin_amdgcn_mfma_f32_16x16x32_f16(a1f[m], b1f[n], acc[m][n], 0, 0, 0);
          acc[m][n] = __builtin_amdgcn_mfma_f32_16x16x32_f16(a1f[m], b2f[n], acc[m][n], 0, 0, 0);
          acc[m][n] = __builtin_amdgcn_mfma_f32_16x16x32_f16(a2f[m], b1f[n], acc[m][n], 0, 0, 0);
        }
    }
  }
#pragma unroll
  for (int m = 0; m < 4; ++m) {
    const int row = row0 + wr*64 + m*16 + (lane >> 4)*4;
#pragma unroll
    for (int n = 0; n < 4; ++n) {
      const int rest = n*16 + (lane & 15);
      int col;
      if (MODE == 2) col = col0*2 + wc*128 + 64 + rest;   // remap to h-part cols
      else           col = col0 + wc*64 + rest;
#pragma unroll
      for (int r = 0; r < 4; ++r) {
        float v = acc[m][n][r] * scale;
        f16 hi = (f16)v;
        C1[(size_t)(row + r)*ldc + col] = hi;
        C2[(size_t)(row + r)*ldc + col] = (f16)(v - (float)hi);
      }
    }
  }
}

// ---------- gates MFMA (fused): sigmoid epilogue; writes rh f32, u f32 ----------
__launch_bounds__(256)
__global__ void k_gatesmf(const f16* __restrict__ P1, const f16* __restrict__ P2,
                          const f16* __restrict__ W1g0, const f16* __restrict__ W2g0,
                          const f16* __restrict__ W1g1, const f16* __restrict__ W2g1,
                          const float* __restrict__ b0, const float* __restrict__ b1,
                          const float* __restrict__ h,
                          float* __restrict__ rh, float* __restrict__ ubuf) {
  const int g = blockIdx.z;
  const f16* W1 = g ? W1g1 : W1g0;
  const f16* W2 = g ? W2g1 : W2g0;
  const float* bias = g ? b1 : b0;
  float* rh_g = rh   + (size_t)g * RRR * UU;
  float* u_g  = ubuf + (size_t)g * RRR * UU;
  __shared__ __align__(16) f16 As1[128*64], As2[128*64], Bs1[128*64], Bs2[128*64];
  const int tid = threadIdx.x;
  const int lane = tid & 63, w = tid >> 6;
  const int wr = w >> 1, wc = w & 1;
  const int R0 = blockIdx.x * 128;
  const int rq = lane >> 3;
  const int gq = ((lane & 7) ^ rq) * 8;

  f32x4 acc[4][4];
#pragma unroll
  for (int m = 0; m < 4; ++m)
#pragma unroll
    for (int n = 0; n < 4; ++n) acc[m][n] = (f32x4){0.f,0.f,0.f,0.f};

  for (int sup = 0; sup < 2; ++sup) {
    const f16* A1 = P1 + (size_t)(2*g + sup)*RRR*CC;
    const f16* A2 = P2 + (size_t)(2*g + sup)*RRR*CC;
    const f16* B1 = W1 + (size_t)sup*16384;
    const f16* B2 = W2 + (size_t)sup*16384;
    for (int k0 = 0; k0 < 128; k0 += 64) {
      __syncthreads();
#pragma unroll
      for (int q = 0; q < 4; ++q) {
        const int rloc = w*32 + q*8;
        gload16(A1 + (size_t)(R0 + rloc + rq)*128 + k0 + gq, As1 + rloc*64);
        gload16(A2 + (size_t)(R0 + rloc + rq)*128 + k0 + gq, As2 + rloc*64);
        gload16(B1 + (size_t)(rloc + rq)*128 + k0 + gq, Bs1 + rloc*64);
        gload16(B2 + (size_t)(rloc + rq)*128 + k0 + gq, Bs2 + rloc*64);
      }
      __syncthreads();
#pragma unroll
      for (int ks = 0; ks < 2; ++ks) {
        const int gk = ks*4 + (lane >> 4);
        f16x8 a1f[4], a2f[4], b1f[4], b2f[4];
#pragma unroll
        for (int m = 0; m < 4; ++m) {
          const int ra = wr*64 + m*16 + (lane & 15);
          const int sa = ra*64 + ((gk ^ (ra & 7))*8);
          a1f[m] = *(const f16x8*)(As1 + sa);
          a2f[m] = *(const f16x8*)(As2 + sa);
          const int rb = wc*64 + m*16 + (lane & 15);
          const int sb = rb*64 + ((gk ^ (rb & 7))*8);
          b1f[m] = *(const f16x8*)(Bs1 + sb);
          b2f[m] = *(const f16x8*)(Bs2 + sb);
        }
#pragma unroll
        for (int m = 0; m < 4; ++m)
#pragma unroll
          for (int n = 0; n < 4; ++n) {
            acc[m][n] = __builtin_amdgcn_mfma_f32_16x16x32_f16(a1f[m], b1f[n], acc[m][n], 0, 0, 0);
            acc[m][n] = __builtin_amdgcn_mfma_f32_16x16x32_f16(a1f[m], b2f[n], acc[m][n], 0, 0, 0);
            acc[m][n] = __builtin_amdgcn_mfma_f32_16x16x32_f16(a2f[m], b1f[n], acc[m][n], 0, 0, 0);
          }
      }
    }
  }
#pragma unroll
  for (int m = 0; m < 4; ++m) {
    const int row = R0 + wr*64 + m*16 + (lane >> 4)*4;
#pragma unroll
    for (int n = 0; n < 4; ++n) {
      const int o = wc*64 + n*16 + (lane & 15);
#pragma unroll
      for (int r = 0; r < 4; ++r) {
        const int R = row + r;
        float v = acc[m][n][r] * 0.00390625f + bias[o];
        float sg = 1.f / (1.f + expf(-v));
        if (o < 64) rh_g[(size_t)R*UU + o] = sg * h[(size_t)R*UU + o];
        else        u_g[(size_t)R*UU + o - 64] = sg;
      }
    }
  }
}

// ---------- candidate (both gates) + GRU update; 256 blocks x 64-row tiles ----------
__launch_bounds__(256)
__global__ void k_candupd(const f16* __restrict__ P1, const f16* __restrict__ P2,
                          const f16* __restrict__ Q1, const f16* __restrict__ Q2,
                          const f16* __restrict__ Wc1g0, const f16* __restrict__ Wc2g0,
                          const f16* __restrict__ Wc1g1, const f16* __restrict__ Wc2g1,
                          const float* __restrict__ b0, const float* __restrict__ b1,
                          const float* __restrict__ ubuf,
                          float* __restrict__ h, float* __restrict__ xh_self,
                          float* __restrict__ xh_next) {
  __shared__ __align__(16) f16 As1[64*64], As2[64*64], Bs1[64*64], Bs2[64*64];
  const int tid = threadIdx.x;
  const int lane = tid & 63, w = tid >> 6;
  const int R0 = blockIdx.x * 64;
  const int rq = lane >> 3;
  const int gq = ((lane & 7) ^ rq) * 8;

  f32x4 acc[2][4];
#pragma unroll
  for (int g = 0; g < 2; ++g)
#pragma unroll
    for (int n = 0; n < 4; ++n) acc[g][n] = (f32x4){0.f,0.f,0.f,0.f};

#pragma unroll
  for (int g = 0; g < 2; ++g) {
    const f16* W1 = g ? Wc1g1 : Wc1g0;
    const f16* W2 = g ? Wc2g1 : Wc2g0;
#pragma unroll
    for (int seg = 0; seg < 4; ++seg) {
      const int sup = seg >> 1, isQ = seg & 1;
      const f16* A1 = isQ ? (Q1 + ((size_t)g*2 + sup)*1048576)
                          : (P1 + (size_t)(2*g + sup)*RRR*CC);
      const f16* A2 = isQ ? (Q2 + ((size_t)g*2 + sup)*1048576)
                          : (P2 + (size_t)(2*g + sup)*RRR*CC);
      const int lda = isQ ? 64 : 128;
      const f16* B1 = W1 + (size_t)sup*8192 + (isQ ? 64 : 0);
      const f16* B2 = W2 + (size_t)sup*8192 + (isQ ? 64 : 0);
      __syncthreads();
#pragma unroll
      for (int q = 0; q < 2; ++q) {
        const int rloc = w*16 + q*8;
        gload16(A1 + (size_t)(R0 + rloc + rq)*lda + gq, As1 + rloc*64);
        gload16(A2 + (size_t)(R0 + rloc + rq)*lda + gq, As2 + rloc*64);
        gload16(B1 + (size_t)(rloc + rq)*128 + gq, Bs1 + rloc*64);
        gload16(B2 + (size_t)(rloc + rq)*128 + gq, Bs2 + rloc*64);
      }
      __syncthreads();
#pragma unroll
      for (int ks = 0; ks < 2; ++ks) {
        const int gk = ks*4 + (lane >> 4);
        const int ra = w*16 + (lane & 15);
        const int sa = ra*64 + ((gk ^ (ra & 7))*8);
        f16x8 a1f = *(const f16x8*)(As1 + sa);
        f16x8 a2f = *(const f16x8*)(As2 + sa);
        f16x8 b1f[4], b2f[4];
#pragma unroll
        for (int n = 0; n < 4; ++n) {
          const int rb = n*16 + (lane & 15);
          const int sb = rb*64 + ((gk ^ (rb & 7))*8);
          b1f[n] = *(const f16x8*)(Bs1 + sb);
          b2f[n] = *(const f16x8*)(Bs2 + sb);
        }
#pragma unroll
        for (int n = 0; n < 4; ++n) {
          acc[g][n] = __builtin_amdgcn_mfma_f32_16x16x32_f16(a1f, b1f[n], acc[g][n], 0, 0, 0);
          acc[g][n] = __builtin_amdgcn_mfma_f32_16x16x32_f16(a1f, b2f[n], acc[g][n], 0, 0, 0);
          acc[g][n] = __builtin_amdgcn_mfma_f32_16x16x32_f16(a2f, b1f[n], acc[g][n], 0, 0, 0);
        }
      }
    }
  }
  // epilogue: c = tanh(acc/256 + bias); u = 0.5(u1+u2); h' = (1-u)h + u*0.5(c1+c2)
#pragma unroll
  for (int n = 0; n < 4; ++n) {
    const int o = n*16 + (lane & 15);
#pragma unroll
    for (int r = 0; r < 4; ++r) {
      const int R = R0 + w*16 + (lane >> 4)*4 + r;
      const size_t idx = (size_t)R*UU + o;
      float c1 = tanhf(acc[0][n][r] * 0.00390625f + b0[o]);
      float c2 = tanhf(acc[1][n][r] * 0.00390625f + b1[o]);
      float u = 0.5f*(ubuf[idx] + ubuf[(size_t)RRR*UU + idx]);
      float cc = 0.5f*(c1 + c2);
      float hn = (1.f - u)*h[idx] + u*cc;
      h[idx] = hn;
      if (xh_self) xh_self[(size_t)R*CC + 64 + o] = hn;
      if (xh_next) xh_next[(size_t)R*CC + o] = hn;
    }
  }
}

// ---------- decoder output + next SX ----------
__global__ void k_out(const float* __restrict__ h1, const float* __restrict__ fow,
                      const float* __restrict__ fob, float* __restrict__ out,
                      float* __restrict__ SX, int p) {
  int R = blockIdx.x*blockDim.x + threadIdx.x;   // 16384
  int b = R & 31, n = R >> 5;
  const float* hr = h1 + (size_t)R*UU;
  float s = fob[0];
#pragma unroll
  for (int u = 0; u < UU; ++u) s = fmaf(hr[u], fow[u], s);
  out[(size_t)b*(NP*NN) + (size_t)p*NN + n] = s;
  SX[R] = s;
}

extern "C" void kernel_launch(void* const* d_in, const int* in_sizes, int n_in,
                              void* d_out, int out_size, void* d_ws, size_t ws_size,
                              hipStream_t stream) {
  (void)in_sizes; (void)n_in; (void)out_size; (void)ws_size;
  const float* x   = (const float*)d_in[0];
  const float* adj = (const float*)d_in[1];
  const float* sm1 = (const float*)d_in[2];
  const float* sm2 = (const float*)d_in[3];
  const float* tm  = (const float*)d_in[4];
  const float* fiw = (const float*)d_in[5];
  const float* fib = (const float*)d_in[6];
  const float* fow = (const float*)d_in[7];
  const float* fob = (const float*)d_in[8];

  float* WS   = (float*)d_ws;
  float* ST   = WS + OFF_ST;
  float* AH   = WS + OFF_AH;
  float* INVD = WS + OFF_INVD;
  float* XH   = WS + OFF_XH;
  float* H    = WS + OFF_H;
  float* RH   = WS + OFF_RH;
  float* Ubuf = WS + OFF_U;
  float* SX   = WS + OFF_SX;
  float* PS   = WS + OFF_PS;
  float* SRow = WS + OFF_SROW;
  f16* ST1  = (f16*)(WS + OFF_ST16A);
  f16* ST2  = (f16*)(WS + OFF_ST16B);
  f16* XHT1 = (f16*)(WS + OFF_XHT1);
  f16* XHT2 = (f16*)(WS + OFF_XHT2);
  f16* RHT1 = (f16*)(WS + OFF_RHT1);
  f16* RHT2 = (f16*)(WS + OFF_RHT2);
  f16* P1   = (f16*)(WS + OFF_P1);
  f16* P2   = (f16*)(WS + OFF_P2);
  f16* Q1   = (f16*)(WS + OFF_Q1);
  f16* Q2   = (f16*)(WS + OFF_Q2);
  f16* WT1  = (f16*)(WS + OFF_WT1);
  f16* WT2  = (f16*)(WS + OFF_WT2);

  // ---- supports ----
  k_build_ah<<<dim3(512,2),256,0,stream>>>(adj, sm1, sm2, AH);
  k_deg<<<dim3(512,2),256,0,stream>>>(AH, INVD);
  k_st<<<dim3(512,4),256,0,stream>>>(AH, INVD, ST);
  k_splitA<<<4096,256,0,stream>>>(ST, ST1, ST2, 2048*512);
  k_srow<<<2048,256,0,stream>>>(ST, SRow);

  // ---- weight transposed split sums ----
  const int widx[8] = {9, 11, 13, 15, 17, 19, 21, 23};
  const int Osz[8]  = {128, 64, 128, 64, 128, 64, 128, 64};
  const size_t woff16[8] = {0, 65536, 98304, 163840, 196608, 262144, 294912, 360448};
  for (int tau = 0; tau < 8; ++tau) {
    int total = 2*2*Osz[tau]*128;
    k_wsumt<<<(total + 255)/256, 256, 0, stream>>>((const float*)d_in[widx[tau]],
                                                   WT1 + woff16[tau], WT2 + woff16[tau],
                                                   Osz[tau]);
  }

  hipMemsetAsync(XH, 0, (size_t)2*RRR*CC*sizeof(float), stream);
  hipMemsetAsync(H,  0, (size_t)2*RRR*UU*sizeof(float), stream);

  const float inv256 = 1.0f/256.0f;

  for (int step = 0; step < TT + NP; ++step) {
    const bool enc = step < TT;
    const int ph = enc ? 0 : 1;
    if (enc)             k_sx<<<64,256,0,stream>>>(x, tm, SX, step);
    else if (step == TT) hipMemsetAsync(SX, 0, 16384*sizeof(float), stream);
    // decoder steps > TT: k_out of previous step wrote SX

    k_ps<<<2048,256,0,stream>>>(ST, SX, PS);

    for (int l = 0; l < 2; ++l) {
      float* xh1  = XH + (size_t)RRR*CC;          // layer-1 input buffer
      float* h_l  = H  + (size_t)l*RRR*UU;
      const size_t lru = (size_t)l*2*128*128;
      const size_t lc  = (size_t)l*2*64*128;
      const f16* Wru1a = WT1 + woff16[ph*4+0] + lru;
      const f16* Wru2a = WT2 + woff16[ph*4+0] + lru;
      const f16* Wru1b = WT1 + woff16[ph*4+2] + lru;
      const f16* Wru2b = WT2 + woff16[ph*4+2] + lru;
      const f16* Wc1a  = WT1 + woff16[ph*4+1] + lc;
      const f16* Wc2a  = WT2 + woff16[ph*4+1] + lc;
      const f16* Wc1b  = WT1 + woff16[ph*4+3] + lc;
      const f16* Wc2b  = WT2 + woff16[ph*4+3] + lc;
      const float* bru  = (const float*)d_in[enc?10:18] + (size_t)l*128;
      const float* bc   = (const float*)d_in[enc?12:20] + (size_t)l*64;
      const float* bru2 = (const float*)d_in[enc?14:22] + (size_t)l*128;
      const float* bc2  = (const float*)d_in[enc?16:24] + (size_t)l*64;

      if (l == 0) {
        // h-part transpose of h0: [512][2048] -> [2048][512]
        k_tsplit<<<dim3(32,8,1),256,0,stream>>>(h_l, 2048, 0, XHT1, XHT2, 0);
        // K1 h-part GEMM (cols i in [64,128))
        k_mm16f<2><<<256,256,0,stream>>>(ST1, ST2, 0, XHT1, XHT2, 0,
                                         P1, P2, 4096, 0, inv256);
        // K1 x-part rank-1 fill (cols i in [0,64))
        k_pxfill<<<2048,256,0,stream>>>(PS, SRow, fiw, fib, P1, P2);
      } else {
        // full transpose of xh1: [512][4096] -> [4096][512]
        k_tsplit<<<dim3(64,8,1),256,0,stream>>>(xh1, 4096, 0, XHT1, XHT2, 0);
        k_mm16f<0><<<512,256,0,stream>>>(ST1, ST2, 0, XHT1, XHT2, 0,
                                         P1, P2, 4096, 0, inv256);
      }
      // K2: gates -> rh, u
      k_gatesmf<<<dim3(128,1,2),256,0,stream>>>(P1, P2, Wru1a, Wru2a, Wru1b, Wru2b,
                                                bru, bru2, h_l, RH, Ubuf);
      // transpose+split rh per gate
      k_tsplit<<<dim3(32,8,2),256,0,stream>>>(RH, 2048, (long long)RRR*UU,
                                              RHT1, RHT2, (long long)2048*512);
      // K3: Q per gate
      k_mm16f<1><<<256,256,0,stream>>>(ST1, ST2, (long long)1024*512,
                                       RHT1, RHT2, (long long)2048*512,
                                       Q1, Q2, 2048, (long long)1024*2048, inv256);
      // K4: candidates + GRU update
      k_candupd<<<256,256,0,stream>>>(P1, P2, Q1, Q2, Wc1a, Wc2a, Wc1b, Wc2b,
                                      bc, bc2, Ubuf, h_l,
                                      (l == 1) ? xh1 : nullptr,   // self h-part (layer 1)
                                      (l == 0) ? xh1 : nullptr);  // next-layer x-part
    }
    if (!enc) {
      int p = step - TT;
      k_out<<<64,256,0,stream>>>(H + (size_t)RRR*UU, fow, fob,
                                 (float*)d_out, SX, p);
    }
  }
}

// Round 10
// 5380.508 us; speedup vs baseline: 1.1175x; 1.0005x over previous
//
#include <hip/hip_runtime.h>
#include <math.h>

#define NN 512
#define BB 32
#define UU 64
#define CC 128
#define TT 12
#define NP 12
#define RRR (NN*BB)   // 16384 rows = (n,b)

typedef _Float16 f16;
typedef f16 f16x8 __attribute__((ext_vector_type(8)));
typedef f16 f16x4 __attribute__((ext_vector_type(4)));
typedef float f32x4 __attribute__((ext_vector_type(4)));

// direct global->LDS DMA, 16B per lane; dst wave-uniform base (lane*16 added by HW)
__device__ __forceinline__ void gload16(const f16* g, f16* l) {
  __builtin_amdgcn_global_load_lds((const __attribute__((address_space(1))) void*)g,
                                   (__attribute__((address_space(3))) void*)l, 16, 0, 0);
}

// ---- workspace layout (float units) ----
static const size_t OFF_ST    = 0;                              // [4][512][512] f32
static const size_t OFF_AH    = OFF_ST   + (size_t)4*512*512;
static const size_t OFF_INVD  = OFF_AH   + (size_t)2*512*512;
static const size_t OFF_XH    = OFF_INVD + 2048;                // [2][16384][128] f32
static const size_t OFF_H     = OFF_XH   + (size_t)2*RRR*CC;    // [2][16384][64] f32
static const size_t OFF_RH    = OFF_H    + (size_t)2*RRR*UU;    // [2][16384][64] f32
static const size_t OFF_U     = OFF_RH   + (size_t)2*RRR*UU;
static const size_t OFF_SX    = OFF_U    + (size_t)2*RRR*UU;    // 16384 f32
static const size_t OFF_PS    = OFF_SX   + 16384;               // 4*512*32 f32
static const size_t OFF_SROW  = OFF_PS   + 65536;               // 2048 f32
static const size_t OFF_F16   = OFF_SROW + 2048;
// f16 regions (float units = f16count/2)
static const size_t OFF_ST16A = OFF_F16;                        // 2048*512 f16
static const size_t OFF_ST16B = OFF_ST16A + 524288;
static const size_t OFF_XHT1  = OFF_ST16B + 524288;             // 4096*512 f16
static const size_t OFF_XHT2  = OFF_XHT1  + 1048576;
static const size_t OFF_RHT1  = OFF_XHT2  + 1048576;            // 2*2048*512 f16
static const size_t OFF_RHT2  = OFF_RHT1  + 1048576;
static const size_t OFF_P1    = OFF_RHT2  + 1048576;            // 2048*4096 f16
static const size_t OFF_P2    = OFF_P1    + 4194304;
static const size_t OFF_Q1    = OFF_P2    + 4194304;            // 4*512*2048 f16
static const size_t OFF_Q2    = OFF_Q1    + 2097152;
static const size_t OFF_WT1   = OFF_Q2    + 2097152;            // 393216 f16
static const size_t OFF_WT2   = OFF_WT1   + 196608;

// ---------- precompute ----------
__global__ void k_build_ah(const float* __restrict__ adj, const float* __restrict__ sm1,
                           const float* __restrict__ sm2, float* __restrict__ ah) {
  int a = blockIdx.y, i = blockIdx.x;
  const float* sm = a ? sm2 : sm1;
  for (int j = threadIdx.x; j < NN; j += blockDim.x) {
    float m = tanhf(0.5f * (sm[i*NN + j] + sm[j*NN + i])) + 1.0f;
    ah[((size_t)a*NN + i)*NN + j] = adj[i*NN + j] * m + ((i == j) ? 1.0f : 0.0f);
  }
}

__global__ void k_deg(const float* __restrict__ ah, float* __restrict__ invd) {
  int a = blockIdx.y, n = blockIdx.x;
  const float* A = ah + (size_t)a*NN*NN;
  __shared__ float sr[256], sc[256];
  int t = threadIdx.x;
  sr[t] = A[(size_t)n*NN + t] + A[(size_t)n*NN + t + 256];
  sc[t] = A[(size_t)t*NN + n] + A[(size_t)(t+256)*NN + n];
  __syncthreads();
  for (int s = 128; s > 0; s >>= 1) {
    if (t < s) { sr[t] += sr[t+s]; sc[t] += sc[t+s]; }
    __syncthreads();
  }
  if (t == 0) {
    float dr = sr[0], dc = sc[0];
    invd[(a*2 + 0)*NN + n] = dr > 0.f ? 1.f/dr : 0.f;
    invd[(a*2 + 1)*NN + n] = dc > 0.f ? 1.f/dc : 0.f;
  }
}

// ST[s][m][n]: s=2a+0: inv_dout[a][n]*ah[a][n][m] ; s=2a+1: inv_din[a][n]*ah[a][m][n]
__global__ void k_st(const float* __restrict__ ah, const float* __restrict__ invd,
                     float* __restrict__ ST) {
  int s = blockIdx.y, m = blockIdx.x;
  int a = s >> 1, dir = s & 1;
  const float* A = ah + (size_t)a*NN*NN;
  const float* inv = invd + (a*2 + dir)*NN;
  float* out = ST + ((size_t)s*NN + m)*NN;
  for (int n = threadIdx.x; n < NN; n += blockDim.x) {
    float v = dir ? A[(size_t)m*NN + n] : A[(size_t)n*NN + m];
    out[n] = inv[n] * v;
  }
}

// row sums of ST (once)
__global__ void k_srow(const float* __restrict__ ST, float* __restrict__ SRow) {
  int row = blockIdx.x;
  int t = threadIdx.x;
  __shared__ float red[256];
  red[t] = ST[(size_t)row*512 + t] + ST[(size_t)row*512 + t + 256];
  __syncthreads();
  for (int s = 128; s > 0; s >>= 1) {
    if (t < s) red[t] += red[t+s];
    __syncthreads();
  }
  if (t == 0) SRow[row] = red[0];
}

// fp16 split of ST with x256 scale
__global__ void k_splitA(const float* __restrict__ s, f16* __restrict__ a1,
                         f16* __restrict__ a2, int total) {
  int i = blockIdx.x*blockDim.x + threadIdx.x;
  if (i >= total) return;
  float v = s[i] * 256.0f;
  f16 hi = (f16)v;
  a1[i] = hi;
  a2[i] = (f16)(v - (float)hi);
}

// weight transpose + sum + x256 split: w [2l][4][128][O] -> wt [2l][2fb][O][128]
__global__ void k_wsumt(const float* __restrict__ w, f16* __restrict__ wt1,
                        f16* __restrict__ wt2, int O) {
  int idx = blockIdx.x*blockDim.x + threadIdx.x;
  int total = 2*2*O*128;
  if (idx >= total) return;
  int i  = idx & 127;
  int o  = (idx >> 7) % O;
  int fb = (idx / (128*O)) & 1;
  int l  = idx / (128*O*2);
  const float* wl = w + (((size_t)(l*4 + fb*2)*128 + i)*O + o);
  float v = (wl[0] + wl[(size_t)128*O]) * 256.0f;
  f16 hi = (f16)v;
  size_t dst = ((size_t)(l*2 + fb)*O + o)*128 + i;
  wt1[dst] = hi;
  wt2[dst] = (f16)(v - (float)hi);
}

// SX[n,b] for encoder step t
__global__ void k_sx(const float* __restrict__ x, const float* __restrict__ tm,
                     float* __restrict__ SX, int t) {
  int R = blockIdx.x*blockDim.x + threadIdx.x;   // 16384
  int b = R & 31, n = R >> 5;
  SX[R] = x[((size_t)b*TT + t)*NN + n] * (tanhf(tm[t*NN + n]) + 1.0f);
}

// PS[s,m][b] = sum_n ST[s,m][n] * SX[n,b]
__launch_bounds__(256)
__global__ void k_ps(const float* __restrict__ ST, const float* __restrict__ SX,
                     float* __restrict__ PS) {
  int row = blockIdx.x;                 // 2048
  int t = threadIdx.x;
  int b = t & 31, g = t >> 5;           // 8 n-groups
  const float* Sr = ST + (size_t)row*512 + g*64;
  const float* Sx = SX + (size_t)g*64*32 + b;
  float p = 0.f;
#pragma unroll
  for (int k = 0; k < 64; ++k) p = fmaf(Sr[k], Sx[(size_t)k*32], p);
  __shared__ float red[8][32];
  red[g][b] = p;
  __syncthreads();
  if (g == 0) {
    float s = 0.f;
#pragma unroll
    for (int q = 0; q < 8; ++q) s += red[q][b];
    PS[(size_t)row*32 + b] = s;
  }
}

// fill P x-part (cols 0..63): P[(sup)][(m,b)][u] = PS*fiw[u] + SRow*fib[u]
__global__ void k_pxfill(const float* __restrict__ PS, const float* __restrict__ SRow,
                         const float* __restrict__ fiw, const float* __restrict__ fib,
                         f16* __restrict__ P1, f16* __restrict__ P2) {
  int idx = blockIdx.x*blockDim.x + threadIdx.x;   // 4*16384*8
  int u8 = idx & 7;
  int R = (idx >> 3) & 16383;
  int sup = idx >> 17;
  int m = R >> 5, b = R & 31;
  float ps = PS[((size_t)sup*512 + m)*32 + b];
  float sr = SRow[(size_t)sup*512 + m];
  f16x8 h1, h2;
#pragma unroll
  for (int j = 0; j < 8; ++j) {
    int u = u8*8 + j;
    float v = ps*fiw[u] + sr*fib[u];
    f16 hi = (f16)v;
    h1[j] = hi;
    h2[j] = (f16)(v - (float)hi);
  }
  size_t dst = (size_t)sup*RRR*CC + (size_t)R*CC + u8*8;
  *(f16x8*)(P1 + dst) = h1;
  *(f16x8*)(P2 + dst) = h2;
}

// transpose + fp16-split: src f32 [512 x lds_], dst f16 [cols x 512]
__launch_bounds__(256)
__global__ void k_tsplit(const float* __restrict__ src, int lds_, long long srcZ,
                         f16* __restrict__ d1, f16* __restrict__ d2, long long dstZ) {
  __shared__ float tile[64][65];
  const float* S = src + (size_t)blockIdx.z*srcZ;
  f16* D1 = d1 + (size_t)blockIdx.z*dstZ;
  f16* D2 = d2 + (size_t)blockIdx.z*dstZ;
  int t = threadIdx.x;
  int c0 = blockIdx.x*64, k0 = blockIdx.y*64;
#pragma unroll
  for (int it = 0; it < 4; ++it) {
    int r = (t >> 4) + it*16;
    int c = (t & 15)*4;
    float4 v = *(const float4*)(S + (size_t)(k0 + r)*lds_ + c0 + c);
    tile[r][c] = v.x; tile[r][c+1] = v.y; tile[r][c+2] = v.z; tile[r][c+3] = v.w;
  }
  __syncthreads();
#pragma unroll
  for (int it = 0; it < 4; ++it) {
    int c = (t >> 4) + it*16;       // dst row (source col)
    int ks = (t & 15)*4;
    f16x4 h1, h2;
#pragma unroll
    for (int j = 0; j < 4; ++j) {
      float v = tile[ks + j][c];
      f16 hi = (f16)v;
      h1[j] = hi;
      h2[j] = (f16)(v - (float)hi);
    }
    *(f16x4*)(D1 + (size_t)(c0 + c)*512 + k0 + ks) = h1;
    *(f16x4*)(D2 + (size_t)(c0 + c)*512 + k0 + ks) = h2;
  }
}

// ---------- fused fp16-split MFMA GEMM: C = (A1B1 + A1B2 + A2B1)*scale ----------
// MODE 0: K1 l=1 full (512 blocks).  MODE 1: K3 (256 blocks, z=2).
// MODE 2: K1 l=0 h-part only (256 blocks, cols remapped to i in [64,128)).
// Epilogue: LDS-staged coalesced f16x8 stores (two passes: hi then lo).
template<int MODE>
__launch_bounds__(256)
__global__ void k_mm16f(const f16* __restrict__ A1g, const f16* __restrict__ A2g, long long aZ,
                        const f16* __restrict__ B1g, const f16* __restrict__ B2g, long long bZ,
                        f16* __restrict__ C1g, f16* __restrict__ C2g, int ldc, long long cZ,
                        float scale) {
  const int bid = blockIdx.x;
  const int c = bid & 7, i = bid >> 3;
  int x, y; long long z;
  if (MODE == 0)      { x = 2*c + (i & 1); y = i >> 1; z = 0; }
  else if (MODE == 1) { z = c >> 2; x = 2*(c & 3) + (i & 1); y = i >> 1; }
  else                { x = 2*c + (i & 1); y = i >> 1; z = 0; }
  const f16* A1 = A1g + z*aZ; const f16* A2 = A2g + z*aZ;
  const f16* B1 = B1g + z*bZ; const f16* B2 = B2g + z*bZ;
  f16* C1 = C1g + z*cZ; f16* C2 = C2g + z*cZ;
  const int row0 = x*128, col0 = y*128;

  __shared__ __align__(16) f16 smem[4*128*64];   // 64 KB
  f16* As1 = smem;          f16* As2 = smem + 8192;
  f16* Bs1 = smem + 16384;  f16* Bs2 = smem + 24576;
  const int tid = threadIdx.x;
  const int lane = tid & 63, w = tid >> 6;
  const int wr = w >> 1, wc = w & 1;
  const int rq = lane >> 3;
  const int gq = ((lane & 7) ^ rq) * 8;

  f32x4 acc[4][4];
#pragma unroll
  for (int m = 0; m < 4; ++m)
#pragma unroll
    for (int n = 0; n < 4; ++n) acc[m][n] = (f32x4){0.f,0.f,0.f,0.f};

  for (int k0 = 0; k0 < 512; k0 += 64) {
    __syncthreads();
#pragma unroll
    for (int q = 0; q < 4; ++q) {
      const int rloc = w*32 + q*8;
      gload16(A1 + (size_t)(row0 + rloc + rq)*512 + k0 + gq, As1 + rloc*64);
      gload16(A2 + (size_t)(row0 + rloc + rq)*512 + k0 + gq, As2 + rloc*64);
      gload16(B1 + (size_t)(col0 + rloc + rq)*512 + k0 + gq, Bs1 + rloc*64);
      gload16(B2 + (size_t)(col0 + rloc + rq)*512 + k0 + gq, Bs2 + rloc*64);
    }
    __syncthreads();
#pragma unroll
    for (int ks = 0; ks < 2; ++ks) {
      const int gk = ks*4 + (lane >> 4);
      f16x8 a1f[4], a2f[4], b1f[4], b2f[4];
#pragma unroll
      for (int m = 0; m < 4; ++m) {
        const int ra = wr*64 + m*16 + (lane & 15);
        const int sa = ra*64 + ((gk ^ (ra & 7))*8);
        a1f[m] = *(const f16x8*)(As1 + sa);
        a2f[m] = *(const f16x8*)(As2 + sa);
        const int rb = wc*64 + m*16 + (lane & 15);
        const int sb = rb*64 + ((gk ^ (rb & 7))*8);
        b1f[m] = *(const f16x8*)(Bs1 + sb);
        b2f[m] = *(const f16x8*)(Bs2 + sb);
      }
#pragma unroll
      for (int m = 0; m < 4; ++m)
#pragma unroll
        for (int n = 0; n < 4; ++n) {
          acc[m][n] = __builtin_amdgcn_mfma_f32_16x16x32_f16(a1f[m], b1f[n], acc[m][n], 0, 0, 0);
          acc[m][n] = __builtin_amdgcn_mfma_f32_16x16x32_f16(a1f[m], b2f[n], acc[m][n], 0, 0, 0);
          acc[m][n] = __builtin_amdgcn_mfma_f32_16x16x32_f16(a2f[m], b1f[n], acc[m][n], 0, 0, 0);
        }
    }
  }

  // ---- coalesced epilogue via LDS: [128][136] f16 tile, hi pass then lo pass ----
  const int STR = 136;                   // padded stride breaks bank alignment
  f16* cst = smem;                       // 128*136*2 B = 34.8 KB <= 64 KB
  __syncthreads();                       // all MFMA LDS reads done
#pragma unroll
  for (int pass = 0; pass < 2; ++pass) {
#pragma unroll
    for (int m = 0; m < 4; ++m)
#pragma unroll
      for (int n = 0; n < 4; ++n)
#pragma unroll
        for (int r = 0; r < 4; ++r) {
          const int rl = wr*64 + m*16 + (lane >> 4)*4 + r;   // local row
          const int cl = wc*64 + n*16 + (lane & 15);         // local col
          float v = acc[m][n][r] * scale;
          f16 hi = (f16)v;
          cst[rl*STR + cl] = pass ? (f16)(v - (float)hi) : hi;
        }
    __syncthreads();
    f16* Cg = pass ? C2 : C1;
#pragma unroll
    for (int cI = 0; cI < 8; ++cI) {
      const int idx = cI*256 + tid;      // 0..2047 chunks of 8 f16
      const int orow = idx >> 4, ocol = (idx & 15)*8;
      f16x8 v = *(const f16x8*)(cst + orow*STR + ocol);
      int gcol;
      if (MODE == 2) gcol = col0*2 + (ocol >> 6)*128 + 64 + (ocol & 63);
      else           gcol = col0 + ocol;
      *(f16x8*)(Cg + (size_t)(row0 + orow)*ldc + gcol) = v;
    }
    __syncthreads();
  }
}

// ---------- gates MFMA (fused): sigmoid epilogue; writes rh f32, u f32 ----------
__launch_bounds__(256)
__global__ void k_gatesmf(const f16* __restrict__ P1, const f16* __restrict__ P2,
                          const f16* __restrict__ W1g0, const f16* __restrict__ W2g0,
                          const f16* __restrict__ W1g1, const f16* __restrict__ W2g1,
                          const float* __restrict__ b0, const float* __restrict__ b1,
                          const float* __restrict__ h,
                          float* __restrict__ rh, float* __restrict__ ubuf) {
  const int g = blockIdx.z;
  const f16* W1 = g ? W1g1 : W1g0;
  const f16* W2 = g ? W2g1 : W2g0;
  const float* bias = g ? b1 : b0;
  float* rh_g = rh   + (size_t)g * RRR * UU;
  float* u_g  = ubuf + (size_t)g * RRR * UU;
  __shared__ __align__(16) f16 As1[128*64], As2[128*64], Bs1[128*64], Bs2[128*64];
  const int tid = threadIdx.x;
  const int lane = tid & 63, w = tid >> 6;
  const int wr = w >> 1, wc = w & 1;
  const int R0 = blockIdx.x * 128;
  const int rq = lane >> 3;
  const int gq = ((lane & 7) ^ rq) * 8;

  f32x4 acc[4][4];
#pragma unroll
  for (int m = 0; m < 4; ++m)
#pragma unroll
    for (int n = 0; n < 4; ++n) acc[m][n] = (f32x4){0.f,0.f,0.f,0.f};

  for (int sup = 0; sup < 2; ++sup) {
    const f16* A1 = P1 + (size_t)(2*g + sup)*RRR*CC;
    const f16* A2 = P2 + (size_t)(2*g + sup)*RRR*CC;
    const f16* B1 = W1 + (size_t)sup*16384;
    const f16* B2 = W2 + (size_t)sup*16384;
    for (int k0 = 0; k0 < 128; k0 += 64) {
      __syncthreads();
#pragma unroll
      for (int q = 0; q < 4; ++q) {
        const int rloc = w*32 + q*8;
        gload16(A1 + (size_t)(R0 + rloc + rq)*128 + k0 + gq, As1 + rloc*64);
        gload16(A2 + (size_t)(R0 + rloc + rq)*128 + k0 + gq, As2 + rloc*64);
        gload16(B1 + (size_t)(rloc + rq)*128 + k0 + gq, Bs1 + rloc*64);
        gload16(B2 + (size_t)(rloc + rq)*128 + k0 + gq, Bs2 + rloc*64);
      }
      __syncthreads();
#pragma unroll
      for (int ks = 0; ks < 2; ++ks) {
        const int gk = ks*4 + (lane >> 4);
        f16x8 a1f[4], a2f[4], b1f[4], b2f[4];
#pragma unroll
        for (int m = 0; m < 4; ++m) {
          const int ra = wr*64 + m*16 + (lane & 15);
          const int sa = ra*64 + ((gk ^ (ra & 7))*8);
          a1f[m] = *(const f16x8*)(As1 + sa);
          a2f[m] = *(const f16x8*)(As2 + sa);
          const int rb = wc*64 + m*16 + (lane & 15);
          const int sb = rb*64 + ((gk ^ (rb & 7))*8);
          b1f[m] = *(const f16x8*)(Bs1 + sb);
          b2f[m] = *(const f16x8*)(Bs2 + sb);
        }
#pragma unroll
        for (int m = 0; m < 4; ++m)
#pragma unroll
          for (int n = 0; n < 4; ++n) {
            acc[m][n] = __builtin_amdgcn_mfma_f32_16x16x32_f16(a1f[m], b1f[n], acc[m][n], 0, 0, 0);
            acc[m][n] = __builtin_amdgcn_mfma_f32_16x16x32_f16(a1f[m], b2f[n], acc[m][n], 0, 0, 0);
            acc[m][n] = __builtin_amdgcn_mfma_f32_16x16x32_f16(a2f[m], b1f[n], acc[m][n], 0, 0, 0);
          }
      }
    }
  }
#pragma unroll
  for (int m = 0; m < 4; ++m) {
    const int row = R0 + wr*64 + m*16 + (lane >> 4)*4;
#pragma unroll
    for (int n = 0; n < 4; ++n) {
      const int o = wc*64 + n*16 + (lane & 15);
#pragma unroll
      for (int r = 0; r < 4; ++r) {
        const int R = row + r;
        float v = acc[m][n][r] * 0.00390625f + bias[o];
        float sg = 1.f / (1.f + expf(-v));
        if (o < 64) rh_g[(size_t)R*UU + o] = sg * h[(size_t)R*UU + o];
        else        u_g[(size_t)R*UU + o - 64] = sg;
      }
    }
  }
}

// ---------- candidate (both gates) + GRU update; 256 blocks x 64-row tiles ----------
__launch_bounds__(256)
__global__ void k_candupd(const f16* __restrict__ P1, const f16* __restrict__ P2,
                          const f16* __restrict__ Q1, const f16* __restrict__ Q2,
                          const f16* __restrict__ Wc1g0, const f16* __restrict__ Wc2g0,
                          const f16* __restrict__ Wc1g1, const f16* __restrict__ Wc2g1,
                          const float* __restrict__ b0, const float* __restrict__ b1,
                          const float* __restrict__ ubuf,
                          float* __restrict__ h, float* __restrict__ xh_self,
                          float* __restrict__ xh_next) {
  __shared__ __align__(16) f16 As1[64*64], As2[64*64], Bs1[64*64], Bs2[64*64];
  const int tid = threadIdx.x;
  const int lane = tid & 63, w = tid >> 6;
  const int R0 = blockIdx.x * 64;
  const int rq = lane >> 3;
  const int gq = ((lane & 7) ^ rq) * 8;

  f32x4 acc[2][4];
#pragma unroll
  for (int g = 0; g < 2; ++g)
#pragma unroll
    for (int n = 0; n < 4; ++n) acc[g][n] = (f32x4){0.f,0.f,0.f,0.f};

#pragma unroll
  for (int g = 0; g < 2; ++g) {
    const f16* W1 = g ? Wc1g1 : Wc1g0;
    const f16* W2 = g ? Wc2g1 : Wc2g0;
#pragma unroll
    for (int seg = 0; seg < 4; ++seg) {
      const int sup = seg >> 1, isQ = seg & 1;
      const f16* A1 = isQ ? (Q1 + ((size_t)g*2 + sup)*1048576)
                          : (P1 + (size_t)(2*g + sup)*RRR*CC);
      const f16* A2 = isQ ? (Q2 + ((size_t)g*2 + sup)*1048576)
                          : (P2 + (size_t)(2*g + sup)*RRR*CC);
      const int lda = isQ ? 64 : 128;
      const f16* B1 = W1 + (size_t)sup*8192 + (isQ ? 64 : 0);
      const f16* B2 = W2 + (size_t)sup*8192 + (isQ ? 64 : 0);
      __syncthreads();
#pragma unroll
      for (int q = 0; q < 2; ++q) {
        const int rloc = w*16 + q*8;
        gload16(A1 + (size_t)(R0 + rloc + rq)*lda + gq, As1 + rloc*64);
        gload16(A2 + (size_t)(R0 + rloc + rq)*lda + gq, As2 + rloc*64);
        gload16(B1 + (size_t)(rloc + rq)*128 + gq, Bs1 + rloc*64);
        gload16(B2 + (size_t)(rloc + rq)*128 + gq, Bs2 + rloc*64);
      }
      __syncthreads();
#pragma unroll
      for (int ks = 0; ks < 2; ++ks) {
        const int gk = ks*4 + (lane >> 4);
        const int ra = w*16 + (lane & 15);
        const int sa = ra*64 + ((gk ^ (ra & 7))*8);
        f16x8 a1f = *(const f16x8*)(As1 + sa);
        f16x8 a2f = *(const f16x8*)(As2 + sa);
        f16x8 b1f[4], b2f[4];
#pragma unroll
        for (int n = 0; n < 4; ++n) {
          const int rb = n*16 + (lane & 15);
          const int sb = rb*64 + ((gk ^ (rb & 7))*8);
          b1f[n] = *(const f16x8*)(Bs1 + sb);
          b2f[n] = *(const f16x8*)(Bs2 + sb);
        }
#pragma unroll
        for (int n = 0; n < 4; ++n) {
          acc[g][n] = __builtin_amdgcn_mfma_f32_16x16x32_f16(a1f, b1f[n], acc[g][n], 0, 0, 0);
          acc[g][n] = __builtin_amdgcn_mfma_f32_16x16x32_f16(a1f, b2f[n], acc[g][n], 0, 0, 0);
          acc[g][n] = __builtin_amdgcn_mfma_f32_16x16x32_f16(a2f, b1f[n], acc[g][n], 0, 0, 0);
        }
      }
    }
  }
  // epilogue: c = tanh(acc/256 + bias); u = 0.5(u1+u2); h' = (1-u)h + u*0.5(c1+c2)
#pragma unroll
  for (int n = 0; n < 4; ++n) {
    const int o = n*16 + (lane & 15);
#pragma unroll
    for (int r = 0; r < 4; ++r) {
      const int R = R0 + w*16 + (lane >> 4)*4 + r;
      const size_t idx = (size_t)R*UU + o;
      float c1 = tanhf(acc[0][n][r] * 0.00390625f + b0[o]);
      float c2 = tanhf(acc[1][n][r] * 0.00390625f + b1[o]);
      float u = 0.5f*(ubuf[idx] + ubuf[(size_t)RRR*UU + idx]);
      float cc = 0.5f*(c1 + c2);
      float hn = (1.f - u)*h[idx] + u*cc;
      h[idx] = hn;
      if (xh_self) xh_self[(size_t)R*CC + 64 + o] = hn;
      if (xh_next) xh_next[(size_t)R*CC + o] = hn;
    }
  }
}

// ---------- decoder output + next SX ----------
__global__ void k_out(const float* __restrict__ h1, const float* __restrict__ fow,
                      const float* __restrict__ fob, float* __restrict__ out,
                      float* __restrict__ SX, int p) {
  int R = blockIdx.x*blockDim.x + threadIdx.x;   // 16384
  int b = R & 31, n = R >> 5;
  const float* hr = h1 + (size_t)R*UU;
  float s = fob[0];
#pragma unroll
  for (int u = 0; u < UU; ++u) s = fmaf(hr[u], fow[u], s);
  out[(size_t)b*(NP*NN) + (size_t)p*NN + n] = s;
  SX[R] = s;
}

extern "C" void kernel_launch(void* const* d_in, const int* in_sizes, int n_in,
                              void* d_out, int out_size, void* d_ws, size_t ws_size,
                              hipStream_t stream) {
  (void)in_sizes; (void)n_in; (void)out_size; (void)ws_size;
  const float* x   = (const float*)d_in[0];
  const float* adj = (const float*)d_in[1];
  const float* sm1 = (const float*)d_in[2];
  const float* sm2 = (const float*)d_in[3];
  const float* tm  = (const float*)d_in[4];
  const float* fiw = (const float*)d_in[5];
  const float* fib = (const float*)d_in[6];
  const float* fow = (const float*)d_in[7];
  const float* fob = (const float*)d_in[8];

  float* WS   = (float*)d_ws;
  float* ST   = WS + OFF_ST;
  float* AH   = WS + OFF_AH;
  float* INVD = WS + OFF_INVD;
  float* XH   = WS + OFF_XH;
  float* H    = WS + OFF_H;
  float* RH   = WS + OFF_RH;
  float* Ubuf = WS + OFF_U;
  float* SX   = WS + OFF_SX;
  float* PS   = WS + OFF_PS;
  float* SRow = WS + OFF_SROW;
  f16* ST1  = (f16*)(WS + OFF_ST16A);
  f16* ST2  = (f16*)(WS + OFF_ST16B);
  f16* XHT1 = (f16*)(WS + OFF_XHT1);
  f16* XHT2 = (f16*)(WS + OFF_XHT2);
  f16* RHT1 = (f16*)(WS + OFF_RHT1);
  f16* RHT2 = (f16*)(WS + OFF_RHT2);
  f16* P1   = (f16*)(WS + OFF_P1);
  f16* P2   = (f16*)(WS + OFF_P2);
  f16* Q1   = (f16*)(WS + OFF_Q1);
  f16* Q2   = (f16*)(WS + OFF_Q2);
  f16* WT1  = (f16*)(WS + OFF_WT1);
  f16* WT2  = (f16*)(WS + OFF_WT2);

  // ---- supports ----
  k_build_ah<<<dim3(512,2),256,0,stream>>>(adj, sm1, sm2, AH);
  k_deg<<<dim3(512,2),256,0,stream>>>(AH, INVD);
  k_st<<<dim3(512,4),256,0,stream>>>(AH, INVD, ST);
  k_splitA<<<4096,256,0,stream>>>(ST, ST1, ST2, 2048*512);
  k_srow<<<2048,256,0,stream>>>(ST, SRow);

  // ---- weight transposed split sums ----
  const int widx[8] = {9, 11, 13, 15, 17, 19, 21, 23};
  const int Osz[8]  = {128, 64, 128, 64, 128, 64, 128, 64};
  const size_t woff16[8] = {0, 65536, 98304, 163840, 196608, 262144, 294912, 360448};
  for (int tau = 0; tau < 8; ++tau) {
    int total = 2*2*Osz[tau]*128;
    k_wsumt<<<(total + 255)/256, 256, 0, stream>>>((const float*)d_in[widx[tau]],
                                                   WT1 + woff16[tau], WT2 + woff16[tau],
                                                   Osz[tau]);
  }

  hipMemsetAsync(XH, 0, (size_t)2*RRR*CC*sizeof(float), stream);
  hipMemsetAsync(H,  0, (size_t)2*RRR*UU*sizeof(float), stream);

  const float inv256 = 1.0f/256.0f;

  for (int step = 0; step < TT + NP; ++step) {
    const bool enc = step < TT;
    const int ph = enc ? 0 : 1;
    if (enc)             k_sx<<<64,256,0,stream>>>(x, tm, SX, step);
    else if (step == TT) hipMemsetAsync(SX, 0, 16384*sizeof(float), stream);
    // decoder steps > TT: k_out of previous step wrote SX

    k_ps<<<2048,256,0,stream>>>(ST, SX, PS);

    for (int l = 0; l < 2; ++l) {
      float* xh1  = XH + (size_t)RRR*CC;          // layer-1 input buffer
      float* h_l  = H  + (size_t)l*RRR*UU;
      const size_t lru = (size_t)l*2*128*128;
      const size_t lc  = (size_t)l*2*64*128;
      const f16* Wru1a = WT1 + woff16[ph*4+0] + lru;
      const f16* Wru2a = WT2 + woff16[ph*4+0] + lru;
      const f16* Wru1b = WT1 + woff16[ph*4+2] + lru;
      const f16* Wru2b = WT2 + woff16[ph*4+2] + lru;
      const f16* Wc1a  = WT1 + woff16[ph*4+1] + lc;
      const f16* Wc2a  = WT2 + woff16[ph*4+1] + lc;
      const f16* Wc1b  = WT1 + woff16[ph*4+3] + lc;
      const f16* Wc2b  = WT2 + woff16[ph*4+3] + lc;
      const float* bru  = (const float*)d_in[enc?10:18] + (size_t)l*128;
      const float* bc   = (const float*)d_in[enc?12:20] + (size_t)l*64;
      const float* bru2 = (const float*)d_in[enc?14:22] + (size_t)l*128;
      const float* bc2  = (const float*)d_in[enc?16:24] + (size_t)l*64;

      if (l == 0) {
        // h-part transpose of h0: [512][2048] -> [2048][512]
        k_tsplit<<<dim3(32,8,1),256,0,stream>>>(h_l, 2048, 0, XHT1, XHT2, 0);
        // K1 h-part GEMM (cols i in [64,128))
        k_mm16f<2><<<256,256,0,stream>>>(ST1, ST2, 0, XHT1, XHT2, 0,
                                         P1, P2, 4096, 0, inv256);
        // K1 x-part rank-1 fill (cols i in [0,64))
        k_pxfill<<<2048,256,0,stream>>>(PS, SRow, fiw, fib, P1, P2);
      } else {
        // full transpose of xh1: [512][4096] -> [4096][512]
        k_tsplit<<<dim3(64,8,1),256,0,stream>>>(xh1, 4096, 0, XHT1, XHT2, 0);
        k_mm16f<0><<<512,256,0,stream>>>(ST1, ST2, 0, XHT1, XHT2, 0,
                                         P1, P2, 4096, 0, inv256);
      }
      // K2: gates -> rh, u
      k_gatesmf<<<dim3(128,1,2),256,0,stream>>>(P1, P2, Wru1a, Wru2a, Wru1b, Wru2b,
                                                bru, bru2, h_l, RH, Ubuf);
      // transpose+split rh per gate
      k_tsplit<<<dim3(32,8,2),256,0,stream>>>(RH, 2048, (long long)RRR*UU,
                                              RHT1, RHT2, (long long)2048*512);
      // K3: Q per gate
      k_mm16f<1><<<256,256,0,stream>>>(ST1, ST2, (long long)1024*512,
                                       RHT1, RHT2, (long long)2048*512,
                                       Q1, Q2, 2048, (long long)1024*2048, inv256);
      // K4: candidates + GRU update
      k_candupd<<<256,256,0,stream>>>(P1, P2, Q1, Q2, Wc1a, Wc2a, Wc1b, Wc2b,
                                      bc, bc2, Ubuf, h_l,
                                      (l == 1) ? xh1 : nullptr,   // self h-part (layer 1)
                                      (l == 0) ? xh1 : nullptr);  // next-layer x-part
    }
    if (!enc) {
      int p = step - TT;
      k_out<<<64,256,0,stream>>>(H + (size_t)RRR*UU, fow, fob,
                                 (float*)d_out, SX, p);
    }
  }
}

// Round 11
// 4473.063 us; speedup vs baseline: 1.3442x; 1.2029x over previous
//
#include <hip/hip_runtime.h>
#include <math.h>

#define NN 512
#define BB 32
#define UU 64
#define CC 128
#define TT 12
#define NP 12
#define RRR (NN*BB)   // 16384 rows = (n,b)

typedef _Float16 f16;
typedef f16 f16x8 __attribute__((ext_vector_type(8)));
typedef f16 f16x4 __attribute__((ext_vector_type(4)));
typedef float f32x4 __attribute__((ext_vector_type(4)));

// direct global->LDS DMA, 16B per lane; dst wave-uniform base (lane*16 added by HW)
__device__ __forceinline__ void gload16(const f16* g, f16* l) {
  __builtin_amdgcn_global_load_lds((const __attribute__((address_space(1))) void*)g,
                                   (__attribute__((address_space(3))) void*)l, 16, 0, 0);
}

// ---- workspace layout (float units) ----
static const size_t OFF_ST    = 0;                              // [4][512][512] f32
static const size_t OFF_AH    = OFF_ST   + (size_t)4*512*512;
static const size_t OFF_INVD  = OFF_AH   + (size_t)2*512*512;
static const size_t OFF_XH    = OFF_INVD + 2048;                // [2][16384][128] f32
static const size_t OFF_H     = OFF_XH   + (size_t)2*RRR*CC;    // [2][16384][64] f32
static const size_t OFF_RH    = OFF_H    + (size_t)2*RRR*UU;    // [2][16384][64] f32
static const size_t OFF_U     = OFF_RH   + (size_t)2*RRR*UU;
static const size_t OFF_SX    = OFF_U    + (size_t)2*RRR*UU;    // 16384 f32
static const size_t OFF_PS    = OFF_SX   + 16384;               // 4*512*32 f32
static const size_t OFF_SROW  = OFF_PS   + 65536;               // 2048 f32
static const size_t OFF_F16   = OFF_SROW + 2048;
// f16 regions (float units = f16count/2)
static const size_t OFF_ST16A = OFF_F16;                        // 2048*512 f16
static const size_t OFF_ST16B = OFF_ST16A + 524288;
static const size_t OFF_XHT1  = OFF_ST16B + 524288;             // 4096*512 f16
static const size_t OFF_XHT2  = OFF_XHT1  + 1048576;
static const size_t OFF_RHT1  = OFF_XHT2  + 1048576;            // 2*2048*512 f16
static const size_t OFF_RHT2  = OFF_RHT1  + 1048576;
static const size_t OFF_P1    = OFF_RHT2  + 1048576;            // 2048*4096 f16
static const size_t OFF_P2    = OFF_P1    + 4194304;
static const size_t OFF_Q1    = OFF_P2    + 4194304;            // 4*512*2048 f16
static const size_t OFF_Q2    = OFF_Q1    + 2097152;
static const size_t OFF_WT1   = OFF_Q2    + 2097152;            // 393216 f16
static const size_t OFF_WT2   = OFF_WT1   + 196608;

// ---------- precompute ----------
__global__ void k_build_ah(const float* __restrict__ adj, const float* __restrict__ sm1,
                           const float* __restrict__ sm2, float* __restrict__ ah) {
  int a = blockIdx.y, i = blockIdx.x;
  const float* sm = a ? sm2 : sm1;
  for (int j = threadIdx.x; j < NN; j += blockDim.x) {
    float m = tanhf(0.5f * (sm[i*NN + j] + sm[j*NN + i])) + 1.0f;
    ah[((size_t)a*NN + i)*NN + j] = adj[i*NN + j] * m + ((i == j) ? 1.0f : 0.0f);
  }
}

__global__ void k_deg(const float* __restrict__ ah, float* __restrict__ invd) {
  int a = blockIdx.y, n = blockIdx.x;
  const float* A = ah + (size_t)a*NN*NN;
  __shared__ float sr[256], sc[256];
  int t = threadIdx.x;
  sr[t] = A[(size_t)n*NN + t] + A[(size_t)n*NN + t + 256];
  sc[t] = A[(size_t)t*NN + n] + A[(size_t)(t+256)*NN + n];
  __syncthreads();
  for (int s = 128; s > 0; s >>= 1) {
    if (t < s) { sr[t] += sr[t+s]; sc[t] += sc[t+s]; }
    __syncthreads();
  }
  if (t == 0) {
    float dr = sr[0], dc = sc[0];
    invd[(a*2 + 0)*NN + n] = dr > 0.f ? 1.f/dr : 0.f;
    invd[(a*2 + 1)*NN + n] = dc > 0.f ? 1.f/dc : 0.f;
  }
}

// ST[s][m][n]: s=2a+0: inv_dout[a][n]*ah[a][n][m] ; s=2a+1: inv_din[a][n]*ah[a][m][n]
__global__ void k_st(const float* __restrict__ ah, const float* __restrict__ invd,
                     float* __restrict__ ST) {
  int s = blockIdx.y, m = blockIdx.x;
  int a = s >> 1, dir = s & 1;
  const float* A = ah + (size_t)a*NN*NN;
  const float* inv = invd + (a*2 + dir)*NN;
  float* out = ST + ((size_t)s*NN + m)*NN;
  for (int n = threadIdx.x; n < NN; n += blockDim.x) {
    float v = dir ? A[(size_t)m*NN + n] : A[(size_t)n*NN + m];
    out[n] = inv[n] * v;
  }
}

// row sums of ST (once)
__global__ void k_srow(const float* __restrict__ ST, float* __restrict__ SRow) {
  int row = blockIdx.x;
  int t = threadIdx.x;
  __shared__ float red[256];
  red[t] = ST[(size_t)row*512 + t] + ST[(size_t)row*512 + t + 256];
  __syncthreads();
  for (int s = 128; s > 0; s >>= 1) {
    if (t < s) red[t] += red[t+s];
    __syncthreads();
  }
  if (t == 0) SRow[row] = red[0];
}

// fp16 split of ST with x256 scale
__global__ void k_splitA(const float* __restrict__ s, f16* __restrict__ a1,
                         f16* __restrict__ a2, int total) {
  int i = blockIdx.x*blockDim.x + threadIdx.x;
  if (i >= total) return;
  float v = s[i] * 256.0f;
  f16 hi = (f16)v;
  a1[i] = hi;
  a2[i] = (f16)(v - (float)hi);
}

// weight transpose + sum + x256 split: w [2l][4][128][O] -> wt [2l][2fb][O][128]
__global__ void k_wsumt(const float* __restrict__ w, f16* __restrict__ wt1,
                        f16* __restrict__ wt2, int O) {
  int idx = blockIdx.x*blockDim.x + threadIdx.x;
  int total = 2*2*O*128;
  if (idx >= total) return;
  int i  = idx & 127;
  int o  = (idx >> 7) % O;
  int fb = (idx / (128*O)) & 1;
  int l  = idx / (128*O*2);
  const float* wl = w + (((size_t)(l*4 + fb*2)*128 + i)*O + o);
  float v = (wl[0] + wl[(size_t)128*O]) * 256.0f;
  f16 hi = (f16)v;
  size_t dst = ((size_t)(l*2 + fb)*O + o)*128 + i;
  wt1[dst] = hi;
  wt2[dst] = (f16)(v - (float)hi);
}

// SX[n,b] for encoder step t
__global__ void k_sx(const float* __restrict__ x, const float* __restrict__ tm,
                     float* __restrict__ SX, int t) {
  int R = blockIdx.x*blockDim.x + threadIdx.x;   // 16384
  int b = R & 31, n = R >> 5;
  SX[R] = x[((size_t)b*TT + t)*NN + n] * (tanhf(tm[t*NN + n]) + 1.0f);
}

// PS[s,m][b] = sum_n ST[s,m][n] * SX[n,b]
__launch_bounds__(256)
__global__ void k_ps(const float* __restrict__ ST, const float* __restrict__ SX,
                     float* __restrict__ PS) {
  int row = blockIdx.x;                 // 2048
  int t = threadIdx.x;
  int b = t & 31, g = t >> 5;           // 8 n-groups
  const float* Sr = ST + (size_t)row*512 + g*64;
  const float* Sx = SX + (size_t)g*64*32 + b;
  float p = 0.f;
#pragma unroll
  for (int k = 0; k < 64; ++k) p = fmaf(Sr[k], Sx[(size_t)k*32], p);
  __shared__ float red[8][32];
  red[g][b] = p;
  __syncthreads();
  if (g == 0) {
    float s = 0.f;
#pragma unroll
    for (int q = 0; q < 8; ++q) s += red[q][b];
    PS[(size_t)row*32 + b] = s;
  }
}

// fill P x-part (cols 0..63): P[(sup)][(m,b)][u] = PS*fiw[u] + SRow*fib[u]
__global__ void k_pxfill(const float* __restrict__ PS, const float* __restrict__ SRow,
                         const float* __restrict__ fiw, const float* __restrict__ fib,
                         f16* __restrict__ P1, f16* __restrict__ P2) {
  int idx = blockIdx.x*blockDim.x + threadIdx.x;   // 4*16384*8
  int u8 = idx & 7;
  int R = (idx >> 3) & 16383;
  int sup = idx >> 17;
  int m = R >> 5, b = R & 31;
  float ps = PS[((size_t)sup*512 + m)*32 + b];
  float sr = SRow[(size_t)sup*512 + m];
  f16x8 h1, h2;
#pragma unroll
  for (int j = 0; j < 8; ++j) {
    int u = u8*8 + j;
    float v = ps*fiw[u] + sr*fib[u];
    f16 hi = (f16)v;
    h1[j] = hi;
    h2[j] = (f16)(v - (float)hi);
  }
  size_t dst = (size_t)sup*RRR*CC + (size_t)R*CC + u8*8;
  *(f16x8*)(P1 + dst) = h1;
  *(f16x8*)(P2 + dst) = h2;
}

// transpose + fp16-split: src f32 [512 x lds_], dst f16 [cols x 512]
__launch_bounds__(256)
__global__ void k_tsplit(const float* __restrict__ src, int lds_, long long srcZ,
                         f16* __restrict__ d1, f16* __restrict__ d2, long long dstZ) {
  __shared__ float tile[64][65];
  const float* S = src + (size_t)blockIdx.z*srcZ;
  f16* D1 = d1 + (size_t)blockIdx.z*dstZ;
  f16* D2 = d2 + (size_t)blockIdx.z*dstZ;
  int t = threadIdx.x;
  int c0 = blockIdx.x*64, k0 = blockIdx.y*64;
#pragma unroll
  for (int it = 0; it < 4; ++it) {
    int r = (t >> 4) + it*16;
    int c = (t & 15)*4;
    float4 v = *(const float4*)(S + (size_t)(k0 + r)*lds_ + c0 + c);
    tile[r][c] = v.x; tile[r][c+1] = v.y; tile[r][c+2] = v.z; tile[r][c+3] = v.w;
  }
  __syncthreads();
#pragma unroll
  for (int it = 0; it < 4; ++it) {
    int c = (t >> 4) + it*16;       // dst row (source col)
    int ks = (t & 15)*4;
    f16x4 h1, h2;
#pragma unroll
    for (int j = 0; j < 4; ++j) {
      float v = tile[ks + j][c];
      f16 hi = (f16)v;
      h1[j] = hi;
      h2[j] = (f16)(v - (float)hi);
    }
    *(f16x4*)(D1 + (size_t)(c0 + c)*512 + k0 + ks) = h1;
    *(f16x4*)(D2 + (size_t)(c0 + c)*512 + k0 + ks) = h2;
  }
}

// ---------- fused fp16-split MFMA GEMM: C = (A1B1 + A1B2 + A2B1)*scale ----------
// 64-row x 128-col tiles for >=2 blocks/CU occupancy.
// MODE 0: K1 l=1 (1024 blocks, 32x32).  MODE 1: K3 (512 blocks, 2z x 16 x 16).
// MODE 2: K1 l=0 h-part (512 blocks, 32x16, cols remapped to i in [64,128)).
template<int MODE>
__launch_bounds__(256)
__global__ void k_mm16f(const f16* __restrict__ A1g, const f16* __restrict__ A2g, long long aZ,
                        const f16* __restrict__ B1g, const f16* __restrict__ B2g, long long bZ,
                        f16* __restrict__ C1g, f16* __restrict__ C2g, int ldc, long long cZ,
                        float scale) {
  const int bid = blockIdx.x;
  const int c = bid & 7, i = bid >> 3;
  int x, y; long long z;
  if (MODE == 0)      { x = 4*c + (i & 3); y = i >> 2; z = 0; }          // 32 x 32
  else if (MODE == 1) { z = c >> 2; x = 4*(c & 3) + (i & 3); y = i >> 2; } // 16 x 16 x 2z
  else                { x = 4*c + (i & 3); y = i >> 2; z = 0; }          // 32 x 16
  const f16* A1 = A1g + z*aZ; const f16* A2 = A2g + z*aZ;
  const f16* B1 = B1g + z*bZ; const f16* B2 = B2g + z*bZ;
  f16* C1 = C1g + z*cZ; f16* C2 = C2g + z*cZ;
  const int row0 = x*64, col0 = y*128;

  __shared__ __align__(16) f16 smem[24576];      // 48 KB
  f16* As1 = smem;          f16* As2 = smem + 4096;
  f16* Bs1 = smem + 8192;   f16* Bs2 = smem + 16384;
  const int tid = threadIdx.x;
  const int lane = tid & 63, w = tid >> 6;
  const int rq = lane >> 3;
  const int gq = ((lane & 7) ^ rq) * 8;

  f32x4 acc[4][2];
#pragma unroll
  for (int m = 0; m < 4; ++m)
#pragma unroll
    for (int n = 0; n < 2; ++n) acc[m][n] = (f32x4){0.f,0.f,0.f,0.f};

  for (int k0 = 0; k0 < 512; k0 += 64) {
    __syncthreads();
#pragma unroll
    for (int q = 0; q < 2; ++q) {
      const int rloc = w*16 + q*8;               // A rows 0..63
      gload16(A1 + (size_t)(row0 + rloc + rq)*512 + k0 + gq, As1 + rloc*64);
      gload16(A2 + (size_t)(row0 + rloc + rq)*512 + k0 + gq, As2 + rloc*64);
    }
#pragma unroll
    for (int q = 0; q < 4; ++q) {
      const int rloc = w*32 + q*8;               // B rows 0..127
      gload16(B1 + (size_t)(col0 + rloc + rq)*512 + k0 + gq, Bs1 + rloc*64);
      gload16(B2 + (size_t)(col0 + rloc + rq)*512 + k0 + gq, Bs2 + rloc*64);
    }
    __syncthreads();
#pragma unroll
    for (int ks = 0; ks < 2; ++ks) {
      const int gk = ks*4 + (lane >> 4);
      f16x8 a1f[4], a2f[4], b1f[2], b2f[2];
#pragma unroll
      for (int m = 0; m < 4; ++m) {
        const int ra = m*16 + (lane & 15);
        const int sa = ra*64 + ((gk ^ (ra & 7))*8);
        a1f[m] = *(const f16x8*)(As1 + sa);
        a2f[m] = *(const f16x8*)(As2 + sa);
      }
#pragma unroll
      for (int n = 0; n < 2; ++n) {
        const int rb = w*32 + n*16 + (lane & 15);
        const int sb = rb*64 + ((gk ^ (rb & 7))*8);
        b1f[n] = *(const f16x8*)(Bs1 + sb);
        b2f[n] = *(const f16x8*)(Bs2 + sb);
      }
#pragma unroll
      for (int m = 0; m < 4; ++m)
#pragma unroll
        for (int n = 0; n < 2; ++n) {
          acc[m][n] = __builtin_amdgcn_mfma_f32_16x16x32_f16(a1f[m], b1f[n], acc[m][n], 0, 0, 0);
          acc[m][n] = __builtin_amdgcn_mfma_f32_16x16x32_f16(a1f[m], b2f[n], acc[m][n], 0, 0, 0);
          acc[m][n] = __builtin_amdgcn_mfma_f32_16x16x32_f16(a2f[m], b1f[n], acc[m][n], 0, 0, 0);
        }
    }
  }

  // ---- coalesced epilogue via LDS: [64][136] f16 tile, hi pass then lo pass ----
  const int STR = 136;
  f16* cst = smem;                       // 64*136*2 B = 17.4 KB
  __syncthreads();
#pragma unroll
  for (int pass = 0; pass < 2; ++pass) {
#pragma unroll
    for (int m = 0; m < 4; ++m)
#pragma unroll
      for (int n = 0; n < 2; ++n)
#pragma unroll
        for (int r = 0; r < 4; ++r) {
          const int rl = m*16 + (lane >> 4)*4 + r;           // local row 0..63
          const int cl = w*32 + n*16 + (lane & 15);          // local col 0..127
          float v = acc[m][n][r] * scale;
          f16 hi = (f16)v;
          cst[rl*STR + cl] = pass ? (f16)(v - (float)hi) : hi;
        }
    __syncthreads();
    f16* Cg = pass ? C2 : C1;
#pragma unroll
    for (int cI = 0; cI < 4; ++cI) {
      const int idx = cI*256 + tid;      // 0..1023 chunks of 8 f16
      const int orow = idx >> 4, ocol = (idx & 15)*8;
      f16x8 v = *(const f16x8*)(cst + orow*STR + ocol);
      int gcol;
      if (MODE == 2) gcol = col0*2 + (ocol >> 6)*128 + 64 + (ocol & 63);
      else           gcol = col0 + ocol;
      *(f16x8*)(Cg + (size_t)(row0 + orow)*ldc + gcol) = v;
    }
    __syncthreads();
  }
}

// ---------- gates MFMA (fused): 64-row tiles; sigmoid epilogue; writes rh f32, u f32 ----------
__launch_bounds__(256)
__global__ void k_gatesmf(const f16* __restrict__ P1, const f16* __restrict__ P2,
                          const f16* __restrict__ W1g0, const f16* __restrict__ W2g0,
                          const f16* __restrict__ W1g1, const f16* __restrict__ W2g1,
                          const float* __restrict__ b0, const float* __restrict__ b1,
                          const float* __restrict__ h,
                          float* __restrict__ rh, float* __restrict__ ubuf) {
  const int g = blockIdx.z;
  const f16* W1 = g ? W1g1 : W1g0;
  const f16* W2 = g ? W2g1 : W2g0;
  const float* bias = g ? b1 : b0;
  float* rh_g = rh   + (size_t)g * RRR * UU;
  float* u_g  = ubuf + (size_t)g * RRR * UU;
  __shared__ __align__(16) f16 smem[24576];      // 48 KB
  f16* As1 = smem;          f16* As2 = smem + 4096;
  f16* Bs1 = smem + 8192;   f16* Bs2 = smem + 16384;
  const int tid = threadIdx.x;
  const int lane = tid & 63, w = tid >> 6;
  const int R0 = blockIdx.x * 64;
  const int rq = lane >> 3;
  const int gq = ((lane & 7) ^ rq) * 8;

  f32x4 acc[4][2];
#pragma unroll
  for (int m = 0; m < 4; ++m)
#pragma unroll
    for (int n = 0; n < 2; ++n) acc[m][n] = (f32x4){0.f,0.f,0.f,0.f};

  for (int sup = 0; sup < 2; ++sup) {
    const f16* A1 = P1 + (size_t)(2*g + sup)*RRR*CC;
    const f16* A2 = P2 + (size_t)(2*g + sup)*RRR*CC;
    const f16* B1 = W1 + (size_t)sup*16384;
    const f16* B2 = W2 + (size_t)sup*16384;
    for (int k0 = 0; k0 < 128; k0 += 64) {
      __syncthreads();
#pragma unroll
      for (int q = 0; q < 1; ++q) {
        const int rloc = w*16 + q*8;
        gload16(A1 + (size_t)(R0 + rloc + rq)*128 + k0 + gq, As1 + rloc*64);
        gload16(A2 + (size_t)(R0 + rloc + rq)*128 + k0 + gq, As2 + rloc*64);
      }
#pragma unroll
      for (int q = 1; q < 2; ++q) {
        const int rloc = w*16 + q*8;
        gload16(A1 + (size_t)(R0 + rloc + rq)*128 + k0 + gq, As1 + rloc*64);
        gload16(A2 + (size_t)(R0 + rloc + rq)*128 + k0 + gq, As2 + rloc*64);
      }
#pragma unroll
      for (int q = 0; q < 4; ++q) {
        const int rloc = w*32 + q*8;
        gload16(B1 + (size_t)(rloc + rq)*128 + k0 + gq, Bs1 + rloc*64);
        gload16(B2 + (size_t)(rloc + rq)*128 + k0 + gq, Bs2 + rloc*64);
      }
      __syncthreads();
#pragma unroll
      for (int ks = 0; ks < 2; ++ks) {
        const int gk = ks*4 + (lane >> 4);
        f16x8 a1f[4], a2f[4], b1f[2], b2f[2];
#pragma unroll
        for (int m = 0; m < 4; ++m) {
          const int ra = m*16 + (lane & 15);
          const int sa = ra*64 + ((gk ^ (ra & 7))*8);
          a1f[m] = *(const f16x8*)(As1 + sa);
          a2f[m] = *(const f16x8*)(As2 + sa);
        }
#pragma unroll
        for (int n = 0; n < 2; ++n) {
          const int rb = w*32 + n*16 + (lane & 15);
          const int sb = rb*64 + ((gk ^ (rb & 7))*8);
          b1f[n] = *(const f16x8*)(Bs1 + sb);
          b2f[n] = *(const f16x8*)(Bs2 + sb);
        }
#pragma unroll
        for (int m = 0; m < 4; ++m)
#pragma unroll
          for (int n = 0; n < 2; ++n) {
            acc[m][n] = __builtin_amdgcn_mfma_f32_16x16x32_f16(a1f[m], b1f[n], acc[m][n], 0, 0, 0);
            acc[m][n] = __builtin_amdgcn_mfma_f32_16x16x32_f16(a1f[m], b2f[n], acc[m][n], 0, 0, 0);
            acc[m][n] = __builtin_amdgcn_mfma_f32_16x16x32_f16(a2f[m], b1f[n], acc[m][n], 0, 0, 0);
          }
      }
    }
  }
#pragma unroll
  for (int m = 0; m < 4; ++m) {
    const int row = R0 + m*16 + (lane >> 4)*4;
#pragma unroll
    for (int n = 0; n < 2; ++n) {
      const int o = w*32 + n*16 + (lane & 15);
#pragma unroll
      for (int r = 0; r < 4; ++r) {
        const int R = row + r;
        float v = acc[m][n][r] * 0.00390625f + bias[o];
        float sg = 1.f / (1.f + expf(-v));
        if (o < 64) rh_g[(size_t)R*UU + o] = sg * h[(size_t)R*UU + o];
        else        u_g[(size_t)R*UU + o - 64] = sg;
      }
    }
  }
}

// ---------- candidate (both gates) + GRU update; 512 blocks x 32-row tiles ----------
__launch_bounds__(256)
__global__ void k_candupd(const f16* __restrict__ P1, const f16* __restrict__ P2,
                          const f16* __restrict__ Q1, const f16* __restrict__ Q2,
                          const f16* __restrict__ Wc1g0, const f16* __restrict__ Wc2g0,
                          const f16* __restrict__ Wc1g1, const f16* __restrict__ Wc2g1,
                          const float* __restrict__ b0, const float* __restrict__ b1,
                          const float* __restrict__ ubuf,
                          float* __restrict__ h, float* __restrict__ xh_self,
                          float* __restrict__ xh_next) {
  __shared__ __align__(16) f16 smem[12288];      // 24 KB
  f16* As1 = smem;          f16* As2 = smem + 2048;
  f16* Bs1 = smem + 4096;   f16* Bs2 = smem + 8192;
  const int tid = threadIdx.x;
  const int lane = tid & 63, w = tid >> 6;
  const int R0 = blockIdx.x * 32;
  const int rq = lane >> 3;
  const int gq = ((lane & 7) ^ rq) * 8;
  const int wm = w & 1, wn = w >> 1;             // wave: m-frag, n-group

  f32x4 acc[2][2];
#pragma unroll
  for (int g = 0; g < 2; ++g)
#pragma unroll
    for (int n = 0; n < 2; ++n) acc[g][n] = (f32x4){0.f,0.f,0.f,0.f};

#pragma unroll
  for (int g = 0; g < 2; ++g) {
    const f16* W1 = g ? Wc1g1 : Wc1g0;
    const f16* W2 = g ? Wc2g1 : Wc2g0;
#pragma unroll
    for (int seg = 0; seg < 4; ++seg) {
      const int sup = seg >> 1, isQ = seg & 1;
      const f16* A1 = isQ ? (Q1 + ((size_t)g*2 + sup)*1048576)
                          : (P1 + (size_t)(2*g + sup)*RRR*CC);
      const f16* A2 = isQ ? (Q2 + ((size_t)g*2 + sup)*1048576)
                          : (P2 + (size_t)(2*g + sup)*RRR*CC);
      const int lda = isQ ? 64 : 128;
      const f16* B1 = W1 + (size_t)sup*8192 + (isQ ? 64 : 0);
      const f16* B2 = W2 + (size_t)sup*8192 + (isQ ? 64 : 0);
      __syncthreads();
      {
        const int rloc = w*8;                    // A rows 0..31
        gload16(A1 + (size_t)(R0 + rloc + rq)*lda + gq, As1 + rloc*64);
        gload16(A2 + (size_t)(R0 + rloc + rq)*lda + gq, As2 + rloc*64);
      }
#pragma unroll
      for (int q = 0; q < 2; ++q) {
        const int rloc = w*16 + q*8;             // B rows 0..63
        gload16(B1 + (size_t)(rloc + rq)*128 + gq, Bs1 + rloc*64);
        gload16(B2 + (size_t)(rloc + rq)*128 + gq, Bs2 + rloc*64);
      }
      __syncthreads();
#pragma unroll
      for (int ks = 0; ks < 2; ++ks) {
        const int gk = ks*4 + (lane >> 4);
        const int ra = wm*16 + (lane & 15);
        const int sa = ra*64 + ((gk ^ (ra & 7))*8);
        f16x8 a1f = *(const f16x8*)(As1 + sa);
        f16x8 a2f = *(const f16x8*)(As2 + sa);
        f16x8 b1f[2], b2f[2];
#pragma unroll
        for (int n = 0; n < 2; ++n) {
          const int rb = wn*32 + n*16 + (lane & 15);
          const int sb = rb*64 + ((gk ^ (rb & 7))*8);
          b1f[n] = *(const f16x8*)(Bs1 + sb);
          b2f[n] = *(const f16x8*)(Bs2 + sb);
        }
#pragma unroll
        for (int n = 0; n < 2; ++n) {
          acc[g][n] = __builtin_amdgcn_mfma_f32_16x16x32_f16(a1f, b1f[n], acc[g][n], 0, 0, 0);
          acc[g][n] = __builtin_amdgcn_mfma_f32_16x16x32_f16(a1f, b2f[n], acc[g][n], 0, 0, 0);
          acc[g][n] = __builtin_amdgcn_mfma_f32_16x16x32_f16(a2f, b1f[n], acc[g][n], 0, 0, 0);
        }
      }
    }
  }
  // epilogue: c = tanh(acc/256 + bias); u = 0.5(u1+u2); h' = (1-u)h + u*0.5(c1+c2)
#pragma unroll
  for (int n = 0; n < 2; ++n) {
    const int o = wn*32 + n*16 + (lane & 15);
#pragma unroll
    for (int r = 0; r < 4; ++r) {
      const int R = R0 + wm*16 + (lane >> 4)*4 + r;
      const size_t idx = (size_t)R*UU + o;
      float c1 = tanhf(acc[0][n][r] * 0.00390625f + b0[o]);
      float c2 = tanhf(acc[1][n][r] * 0.00390625f + b1[o]);
      float u = 0.5f*(ubuf[idx] + ubuf[(size_t)RRR*UU + idx]);
      float cc = 0.5f*(c1 + c2);
      float hn = (1.f - u)*h[idx] + u*cc;
      h[idx] = hn;
      if (xh_self) xh_self[(size_t)R*CC + 64 + o] = hn;
      if (xh_next) xh_next[(size_t)R*CC + o] = hn;
    }
  }
}

// ---------- decoder output + next SX ----------
__global__ void k_out(const float* __restrict__ h1, const float* __restrict__ fow,
                      const float* __restrict__ fob, float* __restrict__ out,
                      float* __restrict__ SX, int p) {
  int R = blockIdx.x*blockDim.x + threadIdx.x;   // 16384
  int b = R & 31, n = R >> 5;
  const float* hr = h1 + (size_t)R*UU;
  float s = fob[0];
#pragma unroll
  for (int u = 0; u < UU; ++u) s = fmaf(hr[u], fow[u], s);
  out[(size_t)b*(NP*NN) + (size_t)p*NN + n] = s;
  SX[R] = s;
}

extern "C" void kernel_launch(void* const* d_in, const int* in_sizes, int n_in,
                              void* d_out, int out_size, void* d_ws, size_t ws_size,
                              hipStream_t stream) {
  (void)in_sizes; (void)n_in; (void)out_size; (void)ws_size;
  const float* x   = (const float*)d_in[0];
  const float* adj = (const float*)d_in[1];
  const float* sm1 = (const float*)d_in[2];
  const float* sm2 = (const float*)d_in[3];
  const float* tm  = (const float*)d_in[4];
  const float* fiw = (const float*)d_in[5];
  const float* fib = (const float*)d_in[6];
  const float* fow = (const float*)d_in[7];
  const float* fob = (const float*)d_in[8];

  float* WS   = (float*)d_ws;
  float* ST   = WS + OFF_ST;
  float* AH   = WS + OFF_AH;
  float* INVD = WS + OFF_INVD;
  float* XH   = WS + OFF_XH;
  float* H    = WS + OFF_H;
  float* RH   = WS + OFF_RH;
  float* Ubuf = WS + OFF_U;
  float* SX   = WS + OFF_SX;
  float* PS   = WS + OFF_PS;
  float* SRow = WS + OFF_SROW;
  f16* ST1  = (f16*)(WS + OFF_ST16A);
  f16* ST2  = (f16*)(WS + OFF_ST16B);
  f16* XHT1 = (f16*)(WS + OFF_XHT1);
  f16* XHT2 = (f16*)(WS + OFF_XHT2);
  f16* RHT1 = (f16*)(WS + OFF_RHT1);
  f16* RHT2 = (f16*)(WS + OFF_RHT2);
  f16* P1   = (f16*)(WS + OFF_P1);
  f16* P2   = (f16*)(WS + OFF_P2);
  f16* Q1   = (f16*)(WS + OFF_Q1);
  f16* Q2   = (f16*)(WS + OFF_Q2);
  f16* WT1  = (f16*)(WS + OFF_WT1);
  f16* WT2  = (f16*)(WS + OFF_WT2);

  // ---- supports ----
  k_build_ah<<<dim3(512,2),256,0,stream>>>(adj, sm1, sm2, AH);
  k_deg<<<dim3(512,2),256,0,stream>>>(AH, INVD);
  k_st<<<dim3(512,4),256,0,stream>>>(AH, INVD, ST);
  k_splitA<<<4096,256,0,stream>>>(ST, ST1, ST2, 2048*512);
  k_srow<<<2048,256,0,stream>>>(ST, SRow);

  // ---- weight transposed split sums ----
  const int widx[8] = {9, 11, 13, 15, 17, 19, 21, 23};
  const int Osz[8]  = {128, 64, 128, 64, 128, 64, 128, 64};
  const size_t woff16[8] = {0, 65536, 98304, 163840, 196608, 262144, 294912, 360448};
  for (int tau = 0; tau < 8; ++tau) {
    int total = 2*2*Osz[tau]*128;
    k_wsumt<<<(total + 255)/256, 256, 0, stream>>>((const float*)d_in[widx[tau]],
                                                   WT1 + woff16[tau], WT2 + woff16[tau],
                                                   Osz[tau]);
  }

  hipMemsetAsync(XH, 0, (size_t)2*RRR*CC*sizeof(float), stream);
  hipMemsetAsync(H,  0, (size_t)2*RRR*UU*sizeof(float), stream);

  const float inv256 = 1.0f/256.0f;

  for (int step = 0; step < TT + NP; ++step) {
    const bool enc = step < TT;
    const int ph = enc ? 0 : 1;
    if (enc)             k_sx<<<64,256,0,stream>>>(x, tm, SX, step);
    else if (step == TT) hipMemsetAsync(SX, 0, 16384*sizeof(float), stream);
    // decoder steps > TT: k_out of previous step wrote SX

    k_ps<<<2048,256,0,stream>>>(ST, SX, PS);

    for (int l = 0; l < 2; ++l) {
      float* xh1  = XH + (size_t)RRR*CC;          // layer-1 input buffer
      float* h_l  = H  + (size_t)l*RRR*UU;
      const size_t lru = (size_t)l*2*128*128;
      const size_t lc  = (size_t)l*2*64*128;
      const f16* Wru1a = WT1 + woff16[ph*4+0] + lru;
      const f16* Wru2a = WT2 + woff16[ph*4+0] + lru;
      const f16* Wru1b = WT1 + woff16[ph*4+2] + lru;
      const f16* Wru2b = WT2 + woff16[ph*4+2] + lru;
      const f16* Wc1a  = WT1 + woff16[ph*4+1] + lc;
      const f16* Wc2a  = WT2 + woff16[ph*4+1] + lc;
      const f16* Wc1b  = WT1 + woff16[ph*4+3] + lc;
      const f16* Wc2b  = WT2 + woff16[ph*4+3] + lc;
      const float* bru  = (const float*)d_in[enc?10:18] + (size_t)l*128;
      const float* bc   = (const float*)d_in[enc?12:20] + (size_t)l*64;
      const float* bru2 = (const float*)d_in[enc?14:22] + (size_t)l*128;
      const float* bc2  = (const float*)d_in[enc?16:24] + (size_t)l*64;

      if (l == 0) {
        // h-part transpose of h0: [512][2048] -> [2048][512]
        k_tsplit<<<dim3(32,8,1),256,0,stream>>>(h_l, 2048, 0, XHT1, XHT2, 0);
        // K1 h-part GEMM (cols i in [64,128))
        k_mm16f<2><<<512,256,0,stream>>>(ST1, ST2, 0, XHT1, XHT2, 0,
                                         P1, P2, 4096, 0, inv256);
        // K1 x-part rank-1 fill (cols i in [0,64))
        k_pxfill<<<2048,256,0,stream>>>(PS, SRow, fiw, fib, P1, P2);
      } else {
        // full transpose of xh1: [512][4096] -> [4096][512]
        k_tsplit<<<dim3(64,8,1),256,0,stream>>>(xh1, 4096, 0, XHT1, XHT2, 0);
        k_mm16f<0><<<1024,256,0,stream>>>(ST1, ST2, 0, XHT1, XHT2, 0,
                                          P1, P2, 4096, 0, inv256);
      }
      // K2: gates -> rh, u
      k_gatesmf<<<dim3(256,1,2),256,0,stream>>>(P1, P2, Wru1a, Wru2a, Wru1b, Wru2b,
                                                bru, bru2, h_l, RH, Ubuf);
      // transpose+split rh per gate
      k_tsplit<<<dim3(32,8,2),256,0,stream>>>(RH, 2048, (long long)RRR*UU,
                                              RHT1, RHT2, (long long)2048*512);
      // K3: Q per gate
      k_mm16f<1><<<512,256,0,stream>>>(ST1, ST2, (long long)1024*512,
                                       RHT1, RHT2, (long long)2048*512,
                                       Q1, Q2, 2048, (long long)1024*2048, inv256);
      // K4: candidates + GRU update
      k_candupd<<<512,256,0,stream>>>(P1, P2, Q1, Q2, Wc1a, Wc2a, Wc1b, Wc2b,
                                      bc, bc2, Ubuf, h_l,
                                      (l == 1) ? xh1 : nullptr,   // self h-part (layer 1)
                                      (l == 0) ? xh1 : nullptr);  // next-layer x-part
    }
    if (!enc) {
      int p = step - TT;
      k_out<<<64,256,0,stream>>>(H + (size_t)RRR*UU, fow, fob,
                                 (float*)d_out, SX, p);
    }
  }
}

// Round 12
// 4300.964 us; speedup vs baseline: 1.3980x; 1.0400x over previous
//
#include <hip/hip_runtime.h>
#include <math.h>

#define NN 512
#define BB 32
#define UU 64
#define CC 128
#define TT 12
#define NP 12
#define RRR (NN*BB)   // 16384 rows = (n,b)

typedef _Float16 f16;
typedef f16 f16x8 __attribute__((ext_vector_type(8)));
typedef f16 f16x4 __attribute__((ext_vector_type(4)));
typedef float f32x4 __attribute__((ext_vector_type(4)));

// direct global->LDS DMA, 16B per lane; dst wave-uniform base (lane*16 added by HW)
__device__ __forceinline__ void gload16(const f16* g, f16* l) {
  __builtin_amdgcn_global_load_lds((const __attribute__((address_space(1))) void*)g,
                                   (__attribute__((address_space(3))) void*)l, 16, 0, 0);
}

// ---- workspace layout (float units) ----
static const size_t OFF_ST    = 0;                              // [4][512][512] f32
static const size_t OFF_AH    = OFF_ST   + (size_t)4*512*512;
static const size_t OFF_INVD  = OFF_AH   + (size_t)2*512*512;
static const size_t OFF_XH    = OFF_INVD + 2048;                // [2][16384][128] f32
static const size_t OFF_H     = OFF_XH   + (size_t)2*RRR*CC;    // [2][16384][64] f32
static const size_t OFF_RH    = OFF_H    + (size_t)2*RRR*UU;    // [2][16384][64] f32
static const size_t OFF_U     = OFF_RH   + (size_t)2*RRR*UU;
static const size_t OFF_SX    = OFF_U    + (size_t)2*RRR*UU;    // 16384 f32
static const size_t OFF_PS    = OFF_SX   + 16384;               // (unused now)
static const size_t OFF_SROW  = OFF_PS   + 65536;               // 2048 f32
static const size_t OFF_F16   = OFF_SROW + 2048;
// f16 regions (float units = f16count/2)
static const size_t OFF_ST16A = OFF_F16;                        // 2048*512 f16
static const size_t OFF_ST16B = OFF_ST16A + 524288;
static const size_t OFF_XHT1  = OFF_ST16B + 524288;             // 4096*512 f16
static const size_t OFF_XHT2  = OFF_XHT1  + 1048576;
static const size_t OFF_RHT1  = OFF_XHT2  + 1048576;            // 2*2048*512 f16
static const size_t OFF_RHT2  = OFF_RHT1  + 1048576;
static const size_t OFF_P1    = OFF_RHT2  + 1048576;            // 2048*4096 f16
static const size_t OFF_P2    = OFF_P1    + 4194304;
static const size_t OFF_Q1    = OFF_P2    + 4194304;            // 4*512*2048 f16
static const size_t OFF_Q2    = OFF_Q1    + 2097152;
static const size_t OFF_WT1   = OFF_Q2    + 2097152;            // 393216 f16
static const size_t OFF_WT2   = OFF_WT1   + 196608;

// ---------- precompute ----------
__global__ void k_build_ah(const float* __restrict__ adj, const float* __restrict__ sm1,
                           const float* __restrict__ sm2, float* __restrict__ ah) {
  int a = blockIdx.y, i = blockIdx.x;
  const float* sm = a ? sm2 : sm1;
  for (int j = threadIdx.x; j < NN; j += blockDim.x) {
    float m = tanhf(0.5f * (sm[i*NN + j] + sm[j*NN + i])) + 1.0f;
    ah[((size_t)a*NN + i)*NN + j] = adj[i*NN + j] * m + ((i == j) ? 1.0f : 0.0f);
  }
}

__global__ void k_deg(const float* __restrict__ ah, float* __restrict__ invd) {
  int a = blockIdx.y, n = blockIdx.x;
  const float* A = ah + (size_t)a*NN*NN;
  __shared__ float sr[256], sc[256];
  int t = threadIdx.x;
  sr[t] = A[(size_t)n*NN + t] + A[(size_t)n*NN + t + 256];
  sc[t] = A[(size_t)t*NN + n] + A[(size_t)(t+256)*NN + n];
  __syncthreads();
  for (int s = 128; s > 0; s >>= 1) {
    if (t < s) { sr[t] += sr[t+s]; sc[t] += sc[t+s]; }
    __syncthreads();
  }
  if (t == 0) {
    float dr = sr[0], dc = sc[0];
    invd[(a*2 + 0)*NN + n] = dr > 0.f ? 1.f/dr : 0.f;
    invd[(a*2 + 1)*NN + n] = dc > 0.f ? 1.f/dc : 0.f;
  }
}

// ST[s][m][n]: s=2a+0: inv_dout[a][n]*ah[a][n][m] ; s=2a+1: inv_din[a][n]*ah[a][m][n]
__global__ void k_st(const float* __restrict__ ah, const float* __restrict__ invd,
                     float* __restrict__ ST) {
  int s = blockIdx.y, m = blockIdx.x;
  int a = s >> 1, dir = s & 1;
  const float* A = ah + (size_t)a*NN*NN;
  const float* inv = invd + (a*2 + dir)*NN;
  float* out = ST + ((size_t)s*NN + m)*NN;
  for (int n = threadIdx.x; n < NN; n += blockDim.x) {
    float v = dir ? A[(size_t)m*NN + n] : A[(size_t)n*NN + m];
    out[n] = inv[n] * v;
  }
}

// row sums of ST (once)
__global__ void k_srow(const float* __restrict__ ST, float* __restrict__ SRow) {
  int row = blockIdx.x;
  int t = threadIdx.x;
  __shared__ float red[256];
  red[t] = ST[(size_t)row*512 + t] + ST[(size_t)row*512 + t + 256];
  __syncthreads();
  for (int s = 128; s > 0; s >>= 1) {
    if (t < s) red[t] += red[t+s];
    __syncthreads();
  }
  if (t == 0) SRow[row] = red[0];
}

// fp16 split of ST with x256 scale
__global__ void k_splitA(const float* __restrict__ s, f16* __restrict__ a1,
                         f16* __restrict__ a2, int total) {
  int i = blockIdx.x*blockDim.x + threadIdx.x;
  if (i >= total) return;
  float v = s[i] * 256.0f;
  f16 hi = (f16)v;
  a1[i] = hi;
  a2[i] = (f16)(v - (float)hi);
}

// weight transpose + sum + x256 split: w [2l][4][128][O] -> wt [2l][2fb][O][128]
__global__ void k_wsumt(const float* __restrict__ w, f16* __restrict__ wt1,
                        f16* __restrict__ wt2, int O) {
  int idx = blockIdx.x*blockDim.x + threadIdx.x;
  int total = 2*2*O*128;
  if (idx >= total) return;
  int i  = idx & 127;
  int o  = (idx >> 7) % O;
  int fb = (idx / (128*O)) & 1;
  int l  = idx / (128*O*2);
  const float* wl = w + (((size_t)(l*4 + fb*2)*128 + i)*O + o);
  float v = (wl[0] + wl[(size_t)128*O]) * 256.0f;
  f16 hi = (f16)v;
  size_t dst = ((size_t)(l*2 + fb)*O + o)*128 + i;
  wt1[dst] = hi;
  wt2[dst] = (f16)(v - (float)hi);
}

// SX[n,b] for encoder step t
__global__ void k_sx(const float* __restrict__ x, const float* __restrict__ tm,
                     float* __restrict__ SX, int t) {
  int R = blockIdx.x*blockDim.x + threadIdx.x;   // 16384
  int b = R & 31, n = R >> 5;
  SX[R] = x[((size_t)b*TT + t)*NN + n] * (tanhf(tm[t*NN + n]) + 1.0f);
}

// fused: PS[row][b] = sum_n ST[row][n]*SX[n,b]; then fill P x-part (cols 0..63)
// P[(sup)][(m,b)][u] = PS*fiw[u] + SRow*fib[u]    (row = sup*512+m, 2048 blocks)
__launch_bounds__(256)
__global__ void k_psfill(const float* __restrict__ ST, const float* __restrict__ SX,
                         const float* __restrict__ SRow,
                         const float* __restrict__ fiw, const float* __restrict__ fib,
                         f16* __restrict__ P1, f16* __restrict__ P2) {
  int row = blockIdx.x;                 // 2048
  int t = threadIdx.x;
  int b = t & 31, g = t >> 5;           // 8 n-groups
  const float* Sr = ST + (size_t)row*512 + g*64;
  const float* Sx = SX + (size_t)g*64*32 + b;
  float p = 0.f;
#pragma unroll
  for (int k = 0; k < 64; ++k) p = fmaf(Sr[k], Sx[(size_t)k*32], p);
  __shared__ float red[8][32];
  __shared__ float ps[32];
  red[g][b] = p;
  __syncthreads();
  if (t < 32) {
    float s = 0.f;
#pragma unroll
    for (int q = 0; q < 8; ++q) s += red[q][t];
    ps[t] = s;
  }
  __syncthreads();
  const float sr = SRow[row];
  const int sup = row >> 9, m = row & 511;
  const int b2 = t >> 3, u8 = t & 7;
  const float psv = ps[b2];
  f16x8 h1, h2;
#pragma unroll
  for (int j = 0; j < 8; ++j) {
    int u = u8*8 + j;
    float v = psv*fiw[u] + sr*fib[u];
    f16 hi = (f16)v;
    h1[j] = hi;
    h2[j] = (f16)(v - (float)hi);
  }
  size_t dst = (size_t)sup*RRR*CC + (size_t)(m*32 + b2)*CC + u8*8;
  *(f16x8*)(P1 + dst) = h1;
  *(f16x8*)(P2 + dst) = h2;
}

// transpose + fp16-split: src f32 [512 x lds_], dst f16 [cols x 512]
__launch_bounds__(256)
__global__ void k_tsplit(const float* __restrict__ src, int lds_, long long srcZ,
                         f16* __restrict__ d1, f16* __restrict__ d2, long long dstZ) {
  __shared__ float tile[64][65];
  const float* S = src + (size_t)blockIdx.z*srcZ;
  f16* D1 = d1 + (size_t)blockIdx.z*dstZ;
  f16* D2 = d2 + (size_t)blockIdx.z*dstZ;
  int t = threadIdx.x;
  int c0 = blockIdx.x*64, k0 = blockIdx.y*64;
#pragma unroll
  for (int it = 0; it < 4; ++it) {
    int r = (t >> 4) + it*16;
    int c = (t & 15)*4;
    float4 v = *(const float4*)(S + (size_t)(k0 + r)*lds_ + c0 + c);
    tile[r][c] = v.x; tile[r][c+1] = v.y; tile[r][c+2] = v.z; tile[r][c+3] = v.w;
  }
  __syncthreads();
#pragma unroll
  for (int it = 0; it < 4; ++it) {
    int c = (t >> 4) + it*16;       // dst row (source col)
    int ks = (t & 15)*4;
    f16x4 h1, h2;
#pragma unroll
    for (int j = 0; j < 4; ++j) {
      float v = tile[ks + j][c];
      f16 hi = (f16)v;
      h1[j] = hi;
      h2[j] = (f16)(v - (float)hi);
    }
    *(f16x4*)(D1 + (size_t)(c0 + c)*512 + k0 + ks) = h1;
    *(f16x4*)(D2 + (size_t)(c0 + c)*512 + k0 + ks) = h2;
  }
}

// ---------- fused fp16-split MFMA GEMM: C = (A1B1 + A1B2 + A2B1)*scale ----------
// 64-row x 128-col tiles for >=2 blocks/CU occupancy.
// MODE 0: K1 l=1 (1024 blocks, 32x32).  MODE 1: K3 (512 blocks, 2z x 16 x 16).
// MODE 2: K1 l=0 h-part (512 blocks, 32x16, cols remapped to i in [64,128)).
template<int MODE>
__launch_bounds__(256)
__global__ void k_mm16f(const f16* __restrict__ A1g, const f16* __restrict__ A2g, long long aZ,
                        const f16* __restrict__ B1g, const f16* __restrict__ B2g, long long bZ,
                        f16* __restrict__ C1g, f16* __restrict__ C2g, int ldc, long long cZ,
                        float scale) {
  const int bid = blockIdx.x;
  const int c = bid & 7, i = bid >> 3;
  int x, y; long long z;
  if (MODE == 0)      { x = 4*c + (i & 3); y = i >> 2; z = 0; }          // 32 x 32
  else if (MODE == 1) { z = c >> 2; x = 4*(c & 3) + (i & 3); y = i >> 2; } // 16 x 16 x 2z
  else                { x = 4*c + (i & 3); y = i >> 2; z = 0; }          // 32 x 16
  const f16* A1 = A1g + z*aZ; const f16* A2 = A2g + z*aZ;
  const f16* B1 = B1g + z*bZ; const f16* B2 = B2g + z*bZ;
  f16* C1 = C1g + z*cZ; f16* C2 = C2g + z*cZ;
  const int row0 = x*64, col0 = y*128;

  __shared__ __align__(16) f16 smem[24576];      // 48 KB
  f16* As1 = smem;          f16* As2 = smem + 4096;
  f16* Bs1 = smem + 8192;   f16* Bs2 = smem + 16384;
  const int tid = threadIdx.x;
  const int lane = tid & 63, w = tid >> 6;
  const int rq = lane >> 3;
  const int gq = ((lane & 7) ^ rq) * 8;

  f32x4 acc[4][2];
#pragma unroll
  for (int m = 0; m < 4; ++m)
#pragma unroll
    for (int n = 0; n < 2; ++n) acc[m][n] = (f32x4){0.f,0.f,0.f,0.f};

  for (int k0 = 0; k0 < 512; k0 += 64) {
    __syncthreads();
#pragma unroll
    for (int q = 0; q < 2; ++q) {
      const int rloc = w*16 + q*8;               // A rows 0..63
      gload16(A1 + (size_t)(row0 + rloc + rq)*512 + k0 + gq, As1 + rloc*64);
      gload16(A2 + (size_t)(row0 + rloc + rq)*512 + k0 + gq, As2 + rloc*64);
    }
#pragma unroll
    for (int q = 0; q < 4; ++q) {
      const int rloc = w*32 + q*8;               // B rows 0..127
      gload16(B1 + (size_t)(col0 + rloc + rq)*512 + k0 + gq, Bs1 + rloc*64);
      gload16(B2 + (size_t)(col0 + rloc + rq)*512 + k0 + gq, Bs2 + rloc*64);
    }
    __syncthreads();
#pragma unroll
    for (int ks = 0; ks < 2; ++ks) {
      const int gk = ks*4 + (lane >> 4);
      f16x8 a1f[4], a2f[4], b1f[2], b2f[2];
#pragma unroll
      for (int m = 0; m < 4; ++m) {
        const int ra = m*16 + (lane & 15);
        const int sa = ra*64 + ((gk ^ (ra & 7))*8);
        a1f[m] = *(const f16x8*)(As1 + sa);
        a2f[m] = *(const f16x8*)(As2 + sa);
      }
#pragma unroll
      for (int n = 0; n < 2; ++n) {
        const int rb = w*32 + n*16 + (lane & 15);
        const int sb = rb*64 + ((gk ^ (rb & 7))*8);
        b1f[n] = *(const f16x8*)(Bs1 + sb);
        b2f[n] = *(const f16x8*)(Bs2 + sb);
      }
#pragma unroll
      for (int m = 0; m < 4; ++m)
#pragma unroll
        for (int n = 0; n < 2; ++n) {
          acc[m][n] = __builtin_amdgcn_mfma_f32_16x16x32_f16(a1f[m], b1f[n], acc[m][n], 0, 0, 0);
          acc[m][n] = __builtin_amdgcn_mfma_f32_16x16x32_f16(a1f[m], b2f[n], acc[m][n], 0, 0, 0);
          acc[m][n] = __builtin_amdgcn_mfma_f32_16x16x32_f16(a2f[m], b1f[n], acc[m][n], 0, 0, 0);
        }
    }
  }

  // ---- coalesced epilogue via LDS: [64][136] f16 tile, hi pass then lo pass ----
  const int STR = 136;
  f16* cst = smem;                       // 64*136*2 B = 17.4 KB
  __syncthreads();
#pragma unroll
  for (int pass = 0; pass < 2; ++pass) {
#pragma unroll
    for (int m = 0; m < 4; ++m)
#pragma unroll
      for (int n = 0; n < 2; ++n)
#pragma unroll
        for (int r = 0; r < 4; ++r) {
          const int rl = m*16 + (lane >> 4)*4 + r;           // local row 0..63
          const int cl = w*32 + n*16 + (lane & 15);          // local col 0..127
          float v = acc[m][n][r] * scale;
          f16 hi = (f16)v;
          cst[rl*STR + cl] = pass ? (f16)(v - (float)hi) : hi;
        }
    __syncthreads();
    f16* Cg = pass ? C2 : C1;
#pragma unroll
    for (int cI = 0; cI < 4; ++cI) {
      const int idx = cI*256 + tid;      // 0..1023 chunks of 8 f16
      const int orow = idx >> 4, ocol = (idx & 15)*8;
      f16x8 v = *(const f16x8*)(cst + orow*STR + ocol);
      int gcol;
      if (MODE == 2) gcol = col0*2 + (ocol >> 6)*128 + 64 + (ocol & 63);
      else           gcol = col0 + ocol;
      *(f16x8*)(Cg + (size_t)(row0 + orow)*ldc + gcol) = v;
    }
    __syncthreads();
  }
}

// ---------- gates MFMA (fused): 32-row tiles (4 blocks/CU); sigmoid epilogue ----------
__launch_bounds__(256)
__global__ void k_gatesmf(const f16* __restrict__ P1, const f16* __restrict__ P2,
                          const f16* __restrict__ W1g0, const f16* __restrict__ W2g0,
                          const f16* __restrict__ W1g1, const f16* __restrict__ W2g1,
                          const float* __restrict__ b0, const float* __restrict__ b1,
                          const float* __restrict__ h,
                          float* __restrict__ rh, float* __restrict__ ubuf) {
  const int g = blockIdx.z;
  const f16* W1 = g ? W1g1 : W1g0;
  const f16* W2 = g ? W2g1 : W2g0;
  const float* bias = g ? b1 : b0;
  float* rh_g = rh   + (size_t)g * RRR * UU;
  float* u_g  = ubuf + (size_t)g * RRR * UU;
  __shared__ __align__(16) f16 smem[20480];      // 40 KB
  f16* As1 = smem;          f16* As2 = smem + 2048;
  f16* Bs1 = smem + 4096;   f16* Bs2 = smem + 12288;
  const int tid = threadIdx.x;
  const int lane = tid & 63, w = tid >> 6;
  const int R0 = blockIdx.x * 32;
  const int rq = lane >> 3;
  const int gq = ((lane & 7) ^ rq) * 8;

  f32x4 acc[2][2];
#pragma unroll
  for (int m = 0; m < 2; ++m)
#pragma unroll
    for (int n = 0; n < 2; ++n) acc[m][n] = (f32x4){0.f,0.f,0.f,0.f};

  for (int sup = 0; sup < 2; ++sup) {
    const f16* A1 = P1 + (size_t)(2*g + sup)*RRR*CC;
    const f16* A2 = P2 + (size_t)(2*g + sup)*RRR*CC;
    const f16* B1 = W1 + (size_t)sup*16384;
    const f16* B2 = W2 + (size_t)sup*16384;
    for (int k0 = 0; k0 < 128; k0 += 64) {
      __syncthreads();
      {
        const int rloc = w*8;                    // A rows 0..31
        gload16(A1 + (size_t)(R0 + rloc + rq)*128 + k0 + gq, As1 + rloc*64);
        gload16(A2 + (size_t)(R0 + rloc + rq)*128 + k0 + gq, As2 + rloc*64);
      }
#pragma unroll
      for (int q = 0; q < 4; ++q) {
        const int rloc = w*32 + q*8;             // B rows 0..127
        gload16(B1 + (size_t)(rloc + rq)*128 + k0 + gq, Bs1 + rloc*64);
        gload16(B2 + (size_t)(rloc + rq)*128 + k0 + gq, Bs2 + rloc*64);
      }
      __syncthreads();
#pragma unroll
      for (int ks = 0; ks < 2; ++ks) {
        const int gk = ks*4 + (lane >> 4);
        f16x8 a1f[2], a2f[2], b1f[2], b2f[2];
#pragma unroll
        for (int m = 0; m < 2; ++m) {
          const int ra = m*16 + (lane & 15);
          const int sa = ra*64 + ((gk ^ (ra & 7))*8);
          a1f[m] = *(const f16x8*)(As1 + sa);
          a2f[m] = *(const f16x8*)(As2 + sa);
        }
#pragma unroll
        for (int n = 0; n < 2; ++n) {
          const int rb = w*32 + n*16 + (lane & 15);
          const int sb = rb*64 + ((gk ^ (rb & 7))*8);
          b1f[n] = *(const f16x8*)(Bs1 + sb);
          b2f[n] = *(const f16x8*)(Bs2 + sb);
        }
#pragma unroll
        for (int m = 0; m < 2; ++m)
#pragma unroll
          for (int n = 0; n < 2; ++n) {
            acc[m][n] = __builtin_amdgcn_mfma_f32_16x16x32_f16(a1f[m], b1f[n], acc[m][n], 0, 0, 0);
            acc[m][n] = __builtin_amdgcn_mfma_f32_16x16x32_f16(a1f[m], b2f[n], acc[m][n], 0, 0, 0);
            acc[m][n] = __builtin_amdgcn_mfma_f32_16x16x32_f16(a2f[m], b1f[n], acc[m][n], 0, 0, 0);
          }
      }
    }
  }
#pragma unroll
  for (int m = 0; m < 2; ++m) {
    const int row = R0 + m*16 + (lane >> 4)*4;
#pragma unroll
    for (int n = 0; n < 2; ++n) {
      const int o = w*32 + n*16 + (lane & 15);
#pragma unroll
      for (int r = 0; r < 4; ++r) {
        const int R = row + r;
        float v = acc[m][n][r] * 0.00390625f + bias[o];
        float sg = 1.f / (1.f + expf(-v));
        if (o < 64) rh_g[(size_t)R*UU + o] = sg * h[(size_t)R*UU + o];
        else        u_g[(size_t)R*UU + o - 64] = sg;
      }
    }
  }
}

// ---------- candidate (both gates) + GRU update; 512 blocks x 32-row tiles ----------
__launch_bounds__(256)
__global__ void k_candupd(const f16* __restrict__ P1, const f16* __restrict__ P2,
                          const f16* __restrict__ Q1, const f16* __restrict__ Q2,
                          const f16* __restrict__ Wc1g0, const f16* __restrict__ Wc2g0,
                          const f16* __restrict__ Wc1g1, const f16* __restrict__ Wc2g1,
                          const float* __restrict__ b0, const float* __restrict__ b1,
                          const float* __restrict__ ubuf,
                          float* __restrict__ h, float* __restrict__ xh_self,
                          float* __restrict__ xh_next) {
  __shared__ __align__(16) f16 smem[12288];      // 24 KB
  f16* As1 = smem;          f16* As2 = smem + 2048;
  f16* Bs1 = smem + 4096;   f16* Bs2 = smem + 8192;
  const int tid = threadIdx.x;
  const int lane = tid & 63, w = tid >> 6;
  const int R0 = blockIdx.x * 32;
  const int rq = lane >> 3;
  const int gq = ((lane & 7) ^ rq) * 8;
  const int wm = w & 1, wn = w >> 1;             // wave: m-frag, n-group

  f32x4 acc[2][2];
#pragma unroll
  for (int g = 0; g < 2; ++g)
#pragma unroll
    for (int n = 0; n < 2; ++n) acc[g][n] = (f32x4){0.f,0.f,0.f,0.f};

#pragma unroll
  for (int g = 0; g < 2; ++g) {
    const f16* W1 = g ? Wc1g1 : Wc1g0;
    const f16* W2 = g ? Wc2g1 : Wc2g0;
#pragma unroll
    for (int seg = 0; seg < 4; ++seg) {
      const int sup = seg >> 1, isQ = seg & 1;
      const f16* A1 = isQ ? (Q1 + ((size_t)g*2 + sup)*1048576)
                          : (P1 + (size_t)(2*g + sup)*RRR*CC);
      const f16* A2 = isQ ? (Q2 + ((size_t)g*2 + sup)*1048576)
                          : (P2 + (size_t)(2*g + sup)*RRR*CC);
      const int lda = isQ ? 64 : 128;
      const f16* B1 = W1 + (size_t)sup*8192 + (isQ ? 64 : 0);
      const f16* B2 = W2 + (size_t)sup*8192 + (isQ ? 64 : 0);
      __syncthreads();
      {
        const int rloc = w*8;                    // A rows 0..31
        gload16(A1 + (size_t)(R0 + rloc + rq)*lda + gq, As1 + rloc*64);
        gload16(A2 + (size_t)(R0 + rloc + rq)*lda + gq, As2 + rloc*64);
      }
#pragma unroll
      for (int q = 0; q < 2; ++q) {
        const int rloc = w*16 + q*8;             // B rows 0..63
        gload16(B1 + (size_t)(rloc + rq)*128 + gq, Bs1 + rloc*64);
        gload16(B2 + (size_t)(rloc + rq)*128 + gq, Bs2 + rloc*64);
      }
      __syncthreads();
#pragma unroll
      for (int ks = 0; ks < 2; ++ks) {
        const int gk = ks*4 + (lane >> 4);
        const int ra = wm*16 + (lane & 15);
        const int sa = ra*64 + ((gk ^ (ra & 7))*8);
        f16x8 a1f = *(const f16x8*)(As1 + sa);
        f16x8 a2f = *(const f16x8*)(As2 + sa);
        f16x8 b1f[2], b2f[2];
#pragma unroll
        for (int n = 0; n < 2; ++n) {
          const int rb = wn*32 + n*16 + (lane & 15);
          const int sb = rb*64 + ((gk ^ (rb & 7))*8);
          b1f[n] = *(const f16x8*)(Bs1 + sb);
          b2f[n] = *(const f16x8*)(Bs2 + sb);
        }
#pragma unroll
        for (int n = 0; n < 2; ++n) {
          acc[g][n] = __builtin_amdgcn_mfma_f32_16x16x32_f16(a1f, b1f[n], acc[g][n], 0, 0, 0);
          acc[g][n] = __builtin_amdgcn_mfma_f32_16x16x32_f16(a1f, b2f[n], acc[g][n], 0, 0, 0);
          acc[g][n] = __builtin_amdgcn_mfma_f32_16x16x32_f16(a2f, b1f[n], acc[g][n], 0, 0, 0);
        }
      }
    }
  }
  // epilogue: c = tanh(acc/256 + bias); u = 0.5(u1+u2); h' = (1-u)h + u*0.5(c1+c2)
#pragma unroll
  for (int n = 0; n < 2; ++n) {
    const int o = wn*32 + n*16 + (lane & 15);
#pragma unroll
    for (int r = 0; r < 4; ++r) {
      const int R = R0 + wm*16 + (lane >> 4)*4 + r;
      const size_t idx = (size_t)R*UU + o;
      float c1 = tanhf(acc[0][n][r] * 0.00390625f + b0[o]);
      float c2 = tanhf(acc[1][n][r] * 0.00390625f + b1[o]);
      float u = 0.5f*(ubuf[idx] + ubuf[(size_t)RRR*UU + idx]);
      float cc = 0.5f*(c1 + c2);
      float hn = (1.f - u)*h[idx] + u*cc;
      h[idx] = hn;
      if (xh_self) xh_self[(size_t)R*CC + 64 + o] = hn;
      if (xh_next) xh_next[(size_t)R*CC + o] = hn;
    }
  }
}

// ---------- decoder output + next SX ----------
__global__ void k_out(const float* __restrict__ h1, const float* __restrict__ fow,
                      const float* __restrict__ fob, float* __restrict__ out,
                      float* __restrict__ SX, int p) {
  int R = blockIdx.x*blockDim.x + threadIdx.x;   // 16384
  int b = R & 31, n = R >> 5;
  const float* hr = h1 + (size_t)R*UU;
  float s = fob[0];
#pragma unroll
  for (int u = 0; u < UU; ++u) s = fmaf(hr[u], fow[u], s);
  out[(size_t)b*(NP*NN) + (size_t)p*NN + n] = s;
  SX[R] = s;
}

extern "C" void kernel_launch(void* const* d_in, const int* in_sizes, int n_in,
                              void* d_out, int out_size, void* d_ws, size_t ws_size,
                              hipStream_t stream) {
  (void)in_sizes; (void)n_in; (void)out_size; (void)ws_size;
  const float* x   = (const float*)d_in[0];
  const float* adj = (const float*)d_in[1];
  const float* sm1 = (const float*)d_in[2];
  const float* sm2 = (const float*)d_in[3];
  const float* tm  = (const float*)d_in[4];
  const float* fiw = (const float*)d_in[5];
  const float* fib = (const float*)d_in[6];
  const float* fow = (const float*)d_in[7];
  const float* fob = (const float*)d_in[8];

  float* WS   = (float*)d_ws;
  float* ST   = WS + OFF_ST;
  float* AH   = WS + OFF_AH;
  float* INVD = WS + OFF_INVD;
  float* XH   = WS + OFF_XH;
  float* H    = WS + OFF_H;
  float* RH   = WS + OFF_RH;
  float* Ubuf = WS + OFF_U;
  float* SX   = WS + OFF_SX;
  float* SRow = WS + OFF_SROW;
  f16* ST1  = (f16*)(WS + OFF_ST16A);
  f16* ST2  = (f16*)(WS + OFF_ST16B);
  f16* XHT1 = (f16*)(WS + OFF_XHT1);
  f16* XHT2 = (f16*)(WS + OFF_XHT2);
  f16* RHT1 = (f16*)(WS + OFF_RHT1);
  f16* RHT2 = (f16*)(WS + OFF_RHT2);
  f16* P1   = (f16*)(WS + OFF_P1);
  f16* P2   = (f16*)(WS + OFF_P2);
  f16* Q1   = (f16*)(WS + OFF_Q1);
  f16* Q2   = (f16*)(WS + OFF_Q2);
  f16* WT1  = (f16*)(WS + OFF_WT1);
  f16* WT2  = (f16*)(WS + OFF_WT2);

  // ---- supports ----
  k_build_ah<<<dim3(512,2),256,0,stream>>>(adj, sm1, sm2, AH);
  k_deg<<<dim3(512,2),256,0,stream>>>(AH, INVD);
  k_st<<<dim3(512,4),256,0,stream>>>(AH, INVD, ST);
  k_splitA<<<4096,256,0,stream>>>(ST, ST1, ST2, 2048*512);
  k_srow<<<2048,256,0,stream>>>(ST, SRow);

  // ---- weight transposed split sums ----
  const int widx[8] = {9, 11, 13, 15, 17, 19, 21, 23};
  const int Osz[8]  = {128, 64, 128, 64, 128, 64, 128, 64};
  const size_t woff16[8] = {0, 65536, 98304, 163840, 196608, 262144, 294912, 360448};
  for (int tau = 0; tau < 8; ++tau) {
    int total = 2*2*Osz[tau]*128;
    k_wsumt<<<(total + 255)/256, 256, 0, stream>>>((const float*)d_in[widx[tau]],
                                                   WT1 + woff16[tau], WT2 + woff16[tau],
                                                   Osz[tau]);
  }

  hipMemsetAsync(XH, 0, (size_t)2*RRR*CC*sizeof(float), stream);
  hipMemsetAsync(H,  0, (size_t)2*RRR*UU*sizeof(float), stream);

  const float inv256 = 1.0f/256.0f;

  for (int step = 0; step < TT + NP; ++step) {
    const bool enc = step < TT;
    const int ph = enc ? 0 : 1;
    if (enc)             k_sx<<<64,256,0,stream>>>(x, tm, SX, step);
    else if (step == TT) hipMemsetAsync(SX, 0, 16384*sizeof(float), stream);
    // decoder steps > TT: k_out of previous step wrote SX

    for (int l = 0; l < 2; ++l) {
      float* xh1  = XH + (size_t)RRR*CC;          // layer-1 input buffer
      float* h_l  = H  + (size_t)l*RRR*UU;
      const size_t lru = (size_t)l*2*128*128;
      const size_t lc  = (size_t)l*2*64*128;
      const f16* Wru1a = WT1 + woff16[ph*4+0] + lru;
      const f16* Wru2a = WT2 + woff16[ph*4+0] + lru;
      const f16* Wru1b = WT1 + woff16[ph*4+2] + lru;
      const f16* Wru2b = WT2 + woff16[ph*4+2] + lru;
      const f16* Wc1a  = WT1 + woff16[ph*4+1] + lc;
      const f16* Wc2a  = WT2 + woff16[ph*4+1] + lc;
      const f16* Wc1b  = WT1 + woff16[ph*4+3] + lc;
      const f16* Wc2b  = WT2 + woff16[ph*4+3] + lc;
      const float* bru  = (const float*)d_in[enc?10:18] + (size_t)l*128;
      const float* bc   = (const float*)d_in[enc?12:20] + (size_t)l*64;
      const float* bru2 = (const float*)d_in[enc?14:22] + (size_t)l*128;
      const float* bc2  = (const float*)d_in[enc?16:24] + (size_t)l*64;

      if (l == 0) {
        // h-part transpose of h0: [512][2048] -> [2048][512]
        k_tsplit<<<dim3(32,8,1),256,0,stream>>>(h_l, 2048, 0, XHT1, XHT2, 0);
        // K1 h-part GEMM (cols i in [64,128))
        k_mm16f<2><<<512,256,0,stream>>>(ST1, ST2, 0, XHT1, XHT2, 0,
                                         P1, P2, 4096, 0, inv256);
        // K1 x-part: fused PS compute + rank-1 fill (cols i in [0,64))
        k_psfill<<<2048,256,0,stream>>>(ST, SX, SRow, fiw, fib, P1, P2);
      } else {
        // full transpose of xh1: [512][4096] -> [4096][512]
        k_tsplit<<<dim3(64,8,1),256,0,stream>>>(xh1, 4096, 0, XHT1, XHT2, 0);
        k_mm16f<0><<<1024,256,0,stream>>>(ST1, ST2, 0, XHT1, XHT2, 0,
                                          P1, P2, 4096, 0, inv256);
      }
      // K2: gates -> rh, u (32-row tiles, 4 blocks/CU)
      k_gatesmf<<<dim3(512,1,2),256,0,stream>>>(P1, P2, Wru1a, Wru2a, Wru1b, Wru2b,
                                                bru, bru2, h_l, RH, Ubuf);
      // transpose+split rh per gate
      k_tsplit<<<dim3(32,8,2),256,0,stream>>>(RH, 2048, (long long)RRR*UU,
                                              RHT1, RHT2, (long long)2048*512);
      // K3: Q per gate
      k_mm16f<1><<<512,256,0,stream>>>(ST1, ST2, (long long)1024*512,
                                       RHT1, RHT2, (long long)2048*512,
                                       Q1, Q2, 2048, (long long)1024*2048, inv256);
      // K4: candidates + GRU update
      k_candupd<<<512,256,0,stream>>>(P1, P2, Q1, Q2, Wc1a, Wc2a, Wc1b, Wc2b,
                                      bc, bc2, Ubuf, h_l,
                                      (l == 1) ? xh1 : nullptr,   // self h-part (layer 1)
                                      (l == 0) ? xh1 : nullptr);  // next-layer x-part
    }
    if (!enc) {
      int p = step - TT;
      k_out<<<64,256,0,stream>>>(H + (size_t)RRR*UU, fow, fob,
                                 (float*)d_out, SX, p);
    }
  }
}